// Round 1
// baseline (6784.039 us; speedup 1.0000x reference)
//
#include <hip/hip_runtime.h>
#include <hip/hip_bf16.h>
#include <math.h>

#define NN   50000
#define EE   800000
#define IN_F 256
#define HH   4
#define DD   32
#define OUT_F 128   // H*D
#define ALPHA 0.2f

// ---- monotonic float<->uint key for atomicMax on floats ----
__device__ __forceinline__ unsigned fkey(float x) {
    unsigned b = __float_as_uint(x);
    return b ^ ((unsigned)((int)b >> 31) | 0x80000000u);
}
__device__ __forceinline__ float fdecode(unsigned k) {
    unsigned b = (k & 0x80000000u) ? (k ^ 0x80000000u) : ~k;
    return __uint_as_float(b);
}

__device__ __forceinline__ float elu_f(float x) {
    return x > 0.0f ? x : expm1f(x);
}

// Kernel 1: ft = node_feature @ W ; a1 = <ft, attn_l> ; a2 = <ft, attn_r>
// One wave per node row; block = 4 waves.
__global__ __launch_bounds__(256) void k_node(const float* __restrict__ nf,
        const float* __restrict__ W,
        const float* __restrict__ attn_l, const float* __restrict__ attn_r,
        float* __restrict__ ft, float* __restrict__ a1, float* __restrict__ a2) {
    __shared__ float rows[4][IN_F];
    const int wave = threadIdx.x >> 6;
    const int lane = threadIdx.x & 63;
    const int row  = blockIdx.x * 4 + wave;
    if (row < NN) {
        float4 rv = *(const float4*)(nf + (size_t)row * IN_F + lane * 4);
        *(float4*)(&rows[wave][lane * 4]) = rv;
    }
    __syncthreads();
    if (row >= NN) return;

    const int c0 = lane * 2;
    float acc0 = 0.f, acc1 = 0.f;
    const float* wp = W + c0;
    #pragma unroll 4
    for (int k = 0; k < IN_F; ++k) {
        float r = rows[wave][k];
        float2 w = *(const float2*)(wp + (size_t)k * OUT_F);
        acc0 = fmaf(r, w.x, acc0);
        acc1 = fmaf(r, w.y, acc1);
    }
    *(float2*)(ft + (size_t)row * OUT_F + c0) = make_float2(acc0, acc1);

    const int h = c0 >> 5, d = c0 & 31;
    float p1 = acc0 * attn_l[h * DD + d] + acc1 * attn_l[h * DD + d + 1];
    float p2 = acc0 * attn_r[h * DD + d] + acc1 * attn_r[h * DD + d + 1];
    #pragma unroll
    for (int o = 8; o >= 1; o >>= 1) {
        p1 += __shfl_xor(p1, o);
        p2 += __shfl_xor(p2, o);
    }
    if ((lane & 15) == 0) {
        a1[row * HH + h] = p1;
        a2[row * HH + h] = p2;
    }
}

// Kernel 2: e_ft = edge_feature @ W (stored into ret2 region);
// logits = leaky_relu(a1[src]+a2[dst]+<e_ft,attn_e>); atomicMax segment max.
__global__ __launch_bounds__(256) void k_edge(const float* __restrict__ ef,
        const float* __restrict__ W, const float* __restrict__ attn_e,
        const int* __restrict__ src, const int* __restrict__ dst,
        const float* __restrict__ a1, const float* __restrict__ a2,
        float* __restrict__ eft_out,       // = ret2 region of d_out
        float* __restrict__ logits, unsigned* __restrict__ mkey) {
    __shared__ float rows[4][IN_F];
    const int wave = threadIdx.x >> 6;
    const int lane = threadIdx.x & 63;
    const int row  = blockIdx.x * 4 + wave;
    if (row < EE) {
        float4 rv = *(const float4*)(ef + (size_t)row * IN_F + lane * 4);
        *(float4*)(&rows[wave][lane * 4]) = rv;
    }
    __syncthreads();
    if (row >= EE) return;

    const int c0 = lane * 2;
    float acc0 = 0.f, acc1 = 0.f;
    const float* wp = W + c0;
    #pragma unroll 4
    for (int k = 0; k < IN_F; ++k) {
        float r = rows[wave][k];
        float2 w = *(const float2*)(wp + (size_t)k * OUT_F);
        acc0 = fmaf(r, w.x, acc0);
        acc1 = fmaf(r, w.y, acc1);
    }
    *(float2*)(eft_out + (size_t)row * OUT_F + c0) = make_float2(acc0, acc1);

    const int h = c0 >> 5, d = c0 & 31;
    float p = acc0 * attn_e[h * DD + d] + acc1 * attn_e[h * DD + d + 1];
    #pragma unroll
    for (int o = 8; o >= 1; o >>= 1) p += __shfl_xor(p, o);

    if ((lane & 15) == 0) {
        const int s = src[row], t = dst[row];
        float lg = a1[s * HH + h] + a2[t * HH + h] + p;
        lg = lg >= 0.0f ? lg : ALPHA * lg;
        logits[(size_t)row * HH + h] = lg;
        atomicMax(&mkey[t * HH + h], fkey(lg));
    }
}

// Kernel 3: ex = exp(logit - m[dst]); s[dst] += ex  (ex overwrites logits buf)
__global__ __launch_bounds__(256) void k_exp(const int* __restrict__ dst,
        float* __restrict__ logits, const unsigned* __restrict__ mkey,
        float* __restrict__ ssum) {
    const int i = blockIdx.x * blockDim.x + threadIdx.x;
    if (i >= EE * HH) return;
    const int e = i >> 2, h = i & 3;
    const int t = dst[e];
    float ex = expf(logits[i] - fdecode(mkey[t * HH + h]));
    logits[i] = ex;
    atomicAdd(&ssum[t * HH + h], ex);
}

// Kernel 4: a = ex/s[dst]; f = (e_ft + ft[src])*a; ret2 = elu(f) in place;
// node_out[dst] += f (node_out aliased onto ret1 region, pre-zeroed).
__global__ __launch_bounds__(256) void k_final(const int* __restrict__ src,
        const int* __restrict__ dst, const float* __restrict__ ft,
        const float* __restrict__ ex, const float* __restrict__ ssum,
        float* __restrict__ ret2, float* __restrict__ node_out) {
    const int wave = threadIdx.x >> 6;
    const int lane = threadIdx.x & 63;
    const int e = blockIdx.x * 4 + wave;
    if (e >= EE) return;
    const int s = src[e], t = dst[e];
    const int c0 = lane * 2, h = c0 >> 5;

    const float a = ex[(size_t)e * HH + h] / ssum[t * HH + h];
    float2 ev = *(const float2*)(ret2 + (size_t)e * OUT_F + c0);
    float2 fv = *(const float2*)(ft + (size_t)s * OUT_F + c0);
    float f0 = (ev.x + fv.x) * a;
    float f1 = (ev.y + fv.y) * a;
    *(float2*)(ret2 + (size_t)e * OUT_F + c0) = make_float2(elu_f(f0), elu_f(f1));
    atomicAdd(&node_out[(size_t)t * OUT_F + c0],     f0);
    atomicAdd(&node_out[(size_t)t * OUT_F + c0 + 1], f1);
}

// Kernel 5: ret1 = elu(node_out) in place (aliased).
__global__ __launch_bounds__(256) void k_elu1(const float* __restrict__ node_out,
        float* __restrict__ ret1) {
    const int i = blockIdx.x * blockDim.x + threadIdx.x;
    if (i < NN * OUT_F) ret1[i] = elu_f(node_out[i]);
}

extern "C" void kernel_launch(void* const* d_in, const int* in_sizes, int n_in,
                              void* d_out, int out_size, void* d_ws, size_t ws_size,
                              hipStream_t stream) {
    const float* nf     = (const float*)d_in[0];
    const float* ef     = (const float*)d_in[1];
    const int*   src    = (const int*)d_in[2];
    const int*   dst    = (const int*)d_in[3];
    const float* W      = (const float*)d_in[4];
    const float* attn_l = (const float*)d_in[5];
    const float* attn_r = (const float*)d_in[6];
    const float* attn_e = (const float*)d_in[7];

    float* ret1 = (float*)d_out;                     // N*128, also node_out accum
    float* ret2 = ret1 + (size_t)NN * OUT_F;         // E*128, also e_ft scratch

    // workspace bump allocator (all offsets 256B-aligned by construction)
    char* w = (char*)d_ws;
    float* ft = (float*)w;      w += (size_t)NN * OUT_F * 4;   // 25.6 MB
    float* a1 = (float*)w;      w += (size_t)NN * HH * 4;
    float* a2 = (float*)w;      w += (size_t)NN * HH * 4;
    float* logits = (float*)w;  w += (size_t)EE * HH * 4;      // 12.8 MB
    unsigned* mkey = (unsigned*)w; w += (size_t)NN * HH * 4;
    float* ssum = (float*)w;    w += (size_t)NN * HH * 4;

    hipMemsetAsync(mkey, 0, (size_t)NN * HH * 4, stream);
    hipMemsetAsync(ssum, 0, (size_t)NN * HH * 4, stream);
    hipMemsetAsync(ret1, 0, (size_t)NN * OUT_F * 4, stream);   // node_out accum

    k_node<<<NN / 4, 256, 0, stream>>>(nf, W, attn_l, attn_r, ft, a1, a2);
    k_edge<<<EE / 4, 256, 0, stream>>>(ef, W, attn_e, src, dst, a1, a2,
                                       ret2, logits, mkey);
    k_exp<<<(EE * HH) / 256, 256, 0, stream>>>(dst, logits, mkey, ssum);
    k_final<<<EE / 4, 256, 0, stream>>>(src, dst, ft, logits, ssum, ret2, ret1);
    k_elu1<<<(NN * OUT_F) / 256, 256, 0, stream>>>(ret1, ret1);
}

// Round 2
// 1376.472 us; speedup vs baseline: 4.9286x; 4.9286x over previous
//
#include <hip/hip_runtime.h>
#include <hip/hip_bf16.h>
#include <math.h>

#define NN    50000
#define EE    800000
#define IN_F  256
#define HH    4
#define DD    32
#define OUT_F 128
#define ALPHA 0.2f

typedef float f32x4 __attribute__((ext_vector_type(4)));
typedef short bf16x8 __attribute__((ext_vector_type(8)));

// ---- monotonic float<->uint key for atomicMax on floats ----
__device__ __forceinline__ unsigned fkey(float x) {
    unsigned b = __float_as_uint(x);
    return b ^ ((unsigned)((int)b >> 31) | 0x80000000u);
}
__device__ __forceinline__ float fdecode(unsigned k) {
    unsigned b = (k & 0x80000000u) ? (k ^ 0x80000000u) : ~k;
    return __uint_as_float(b);
}
__device__ __forceinline__ float elu_f(float x) { return x > 0.0f ? x : expm1f(x); }

// fp32 -> bf16 (RNE) and back
__device__ __forceinline__ unsigned short f2bf(float x) {
    union { float f; unsigned u; } v; v.f = x;
    unsigned r = (v.u + 0x7FFFu + ((v.u >> 16) & 1u)) >> 16;
    return (unsigned short)r;
}
__device__ __forceinline__ float bf2f(unsigned short h) {
    union { unsigned u; float f; } v; v.u = ((unsigned)h) << 16; return v.f;
}

// Pack W (256x128 f32) into MFMA B-fragment order, split hi/lo bf16.
// Layout: idx = ((t*8 + cf)*64 + lane)*8 + j  ->  W[32t + 8*(lane>>4) + j][16cf + (lane&15)]
__global__ __launch_bounds__(256) void k_prepw(const float* __restrict__ W,
        unsigned short* __restrict__ Whp, unsigned short* __restrict__ Wlp) {
    int i = blockIdx.x * 256 + threadIdx.x;        // 32768 total
    int j = i & 7, lane = (i >> 3) & 63, cf = (i >> 9) & 7, t = i >> 12;
    int krow = 32 * t + 8 * (lane >> 4) + j;
    int col  = 16 * cf + (lane & 15);
    float x = W[krow * OUT_F + col];
    unsigned short h = f2bf(x);
    unsigned short lo = f2bf(x - bf2f(h));
    Whp[i] = h; Wlp[i] = lo;
}

// Fused GEMM (64 rows x 128 cols, K=256) + attention-dot epilogue.
// MODE 0: node -> Y=ft, o1=a1, o2=a2 (dots with attn_l/attn_r)
// MODE 1: edge -> Y=e_ft(ret2), o1=logits[H][E], dot with attn_e, + gather a1/a2, atomicMax mkey
template <int MODE>
__global__ __launch_bounds__(256) void k_gemm(const float* __restrict__ X, int M,
        const unsigned short* __restrict__ Whp, const unsigned short* __restrict__ Wlp,
        const float* __restrict__ av0, const float* __restrict__ av1,
        const int* __restrict__ src, const int* __restrict__ dst,
        const float* __restrict__ a1, const float* __restrict__ a2,
        float* __restrict__ Y, float* __restrict__ o1, float* __restrict__ o2,
        unsigned* __restrict__ mkey) {
    __shared__ unsigned short Ah[64 * 256];   // 32 KB, XOR-swizzled
    __shared__ unsigned short Al[64 * 256];   // 32 KB

    const int tid = threadIdx.x;
    const int w = tid >> 6;          // wave = head
    const int l = tid & 63;
    const int base = blockIdx.x * 64;

    // ---- B-fragment preload (registers, L2-resident packed W) ----
    bf16x8 Bh[8][2], Bl[8][2];
    #pragma unroll
    for (int t = 0; t < 8; ++t)
        #pragma unroll
        for (int c = 0; c < 2; ++c) {
            size_t off = ((size_t)((t * 8) + (w * 2 + c)) * 64 + l) * 8;
            Bh[t][c] = *(const bf16x8*)(Whp + off);
            Bl[t][c] = *(const bf16x8*)(Wlp + off);
        }

    // ---- stage A tile (64x256 f32 -> hi/lo bf16 in LDS, swizzled) ----
    #pragma unroll
    for (int it = 0; it < 8; ++it) {
        int chunk = it * 256 + tid;            // 0..2047
        int rl = chunk >> 5;                   // local row
        int c0 = (chunk & 31) * 8;             // col start
        int gr = base + rl; if (gr > M - 1) gr = M - 1;
        const float* p = X + (size_t)gr * IN_F + c0;
        float4 u0 = *(const float4*)(p);
        float4 u1 = *(const float4*)(p + 4);
        unsigned short h[8], lo[8];
        float xs[8] = {u0.x, u0.y, u0.z, u0.w, u1.x, u1.y, u1.z, u1.w};
        #pragma unroll
        for (int k = 0; k < 8; ++k) {
            h[k] = f2bf(xs[k]);
            lo[k] = f2bf(xs[k] - bf2f(h[k]));
        }
        unsigned ba = (unsigned)(rl * 512 + c0 * 2) ^ (unsigned)((rl & 7) << 4);
        *(bf16x8*)((char*)Ah + ba) = *(const bf16x8*)h;
        *(bf16x8*)((char*)Al + ba) = *(const bf16x8*)lo;
    }
    __syncthreads();

    // ---- MFMA main loop: 4 rowfrags x 8 ksteps x 2 colfrags x 3 (split) ----
    f32x4 acc[4][2];
    #pragma unroll
    for (int rf = 0; rf < 4; ++rf)
        #pragma unroll
        for (int c = 0; c < 2; ++c)
            acc[rf][c] = (f32x4){0.f, 0.f, 0.f, 0.f};

    #pragma unroll
    for (int rf = 0; rf < 4; ++rf) {
        const int row = rf * 16 + (l & 15);
        #pragma unroll
        for (int t = 0; t < 8; ++t) {
            unsigned ba = (unsigned)(row * 512 + (32 * t + 8 * (l >> 4)) * 2)
                        ^ (unsigned)((row & 7) << 4);
            bf16x8 ah = *(const bf16x8*)((const char*)Ah + ba);
            bf16x8 al = *(const bf16x8*)((const char*)Al + ba);
            #pragma unroll
            for (int c = 0; c < 2; ++c) {
                acc[rf][c] = __builtin_amdgcn_mfma_f32_16x16x32_bf16(ah, Bh[t][c], acc[rf][c], 0, 0, 0);
                acc[rf][c] = __builtin_amdgcn_mfma_f32_16x16x32_bf16(al, Bh[t][c], acc[rf][c], 0, 0, 0);
                acc[rf][c] = __builtin_amdgcn_mfma_f32_16x16x32_bf16(ah, Bl[t][c], acc[rf][c], 0, 0, 0);
            }
        }
    }

    // ---- store Y (ft / e_ft) ----
    #pragma unroll
    for (int rf = 0; rf < 4; ++rf)
        #pragma unroll
        for (int c = 0; c < 2; ++c)
            #pragma unroll
            for (int r = 0; r < 4; ++r) {
                int grow = base + rf * 16 + (l >> 4) * 4 + r;
                if (grow < M)
                    Y[(size_t)grow * OUT_F + w * 32 + c * 16 + (l & 15)] = acc[rf][c][r];
            }

    // ---- attention-dot epilogue (wave w == head w) ----
    const float b0 = av0[w * DD + (l & 15)];
    const float b1 = av0[w * DD + 16 + (l & 15)];
    float c0v = 0.f, c1v = 0.f;
    if (MODE == 0) { c0v = av1[w * DD + (l & 15)]; c1v = av1[w * DD + 16 + (l & 15)]; }

    #pragma unroll
    for (int rf = 0; rf < 4; ++rf) {
        float p[4], q[4];
        #pragma unroll
        for (int r = 0; r < 4; ++r) {
            p[r] = acc[rf][0][r] * b0 + acc[rf][1][r] * b1;
            q[r] = (MODE == 0) ? (acc[rf][0][r] * c0v + acc[rf][1][r] * c1v) : 0.f;
        }
        #pragma unroll
        for (int o = 1; o <= 8; o <<= 1)
            #pragma unroll
            for (int r = 0; r < 4; ++r) {
                p[r] += __shfl_xor(p[r], o);
                if (MODE == 0) q[r] += __shfl_xor(q[r], o);
            }
        if ((l & 15) == 0) {
            int rbase = rf * 16 + (l >> 4) * 4;
            #pragma unroll
            for (int r = 0; r < 4; ++r) {
                int grow = base + rbase + r;
                if (MODE == 0) {
                    if (grow < M) { o1[(size_t)grow * HH + w] = p[r]; o2[(size_t)grow * HH + w] = q[r]; }
                } else {
                    int s = src[grow], t2 = dst[grow];
                    float lg = a1[(size_t)s * HH + w] + a2[(size_t)t2 * HH + w] + p[r];
                    lg = fmaxf(lg, ALPHA * lg);
                    o1[(size_t)w * EE + grow] = lg;
                    atomicMax(&mkey[t2 * HH + w], fkey(lg));
                }
            }
        }
    }
}

// ex = exp(logit - m[dst]); ssum[dst] += ex   (logits layout [H][E], in-place)
__global__ __launch_bounds__(256) void k_exp(const int* __restrict__ dst,
        float* __restrict__ logits, const unsigned* __restrict__ mkey,
        float* __restrict__ ssum) {
    const int i = blockIdx.x * blockDim.x + threadIdx.x;
    if (i >= EE * HH) return;
    const int h = i / EE, e = i - h * EE;
    const int t = dst[e];
    float ex = expf(logits[i] - fdecode(mkey[t * HH + h]));
    logits[i] = ex;
    atomicAdd(&ssum[t * HH + h], ex);
}

// a = ex/s[dst]; f = (e_ft + ft[src])*a; ret2 = elu(f) in place; node_out[dst] += f
__global__ __launch_bounds__(256) void k_final(const int* __restrict__ src,
        const int* __restrict__ dst, const float* __restrict__ ft,
        const float* __restrict__ ex, const float* __restrict__ ssum,
        float* __restrict__ ret2, float* __restrict__ node_out) {
    const int wave = threadIdx.x >> 6;
    const int lane = threadIdx.x & 63;
    const int e = blockIdx.x * 4 + wave;
    if (e >= EE) return;
    const int s = src[e], t = dst[e];
    const int c0 = lane * 2, h = c0 >> 5;

    const float a = ex[(size_t)h * EE + e] / ssum[t * HH + h];
    float2 ev = *(const float2*)(ret2 + (size_t)e * OUT_F + c0);
    float2 fv = *(const float2*)(ft + (size_t)s * OUT_F + c0);
    float f0 = (ev.x + fv.x) * a;
    float f1 = (ev.y + fv.y) * a;
    *(float2*)(ret2 + (size_t)e * OUT_F + c0) = make_float2(elu_f(f0), elu_f(f1));
    atomicAdd(&node_out[(size_t)t * OUT_F + c0],     f0);
    atomicAdd(&node_out[(size_t)t * OUT_F + c0 + 1], f1);
}

__global__ __launch_bounds__(256) void k_elu1(const float* __restrict__ node_out,
        float* __restrict__ ret1) {
    const int i = blockIdx.x * blockDim.x + threadIdx.x;
    if (i < NN * OUT_F) ret1[i] = elu_f(node_out[i]);
}

extern "C" void kernel_launch(void* const* d_in, const int* in_sizes, int n_in,
                              void* d_out, int out_size, void* d_ws, size_t ws_size,
                              hipStream_t stream) {
    const float* nf     = (const float*)d_in[0];
    const float* ef     = (const float*)d_in[1];
    const int*   src    = (const int*)d_in[2];
    const int*   dst    = (const int*)d_in[3];
    const float* W      = (const float*)d_in[4];
    const float* attn_l = (const float*)d_in[5];
    const float* attn_r = (const float*)d_in[6];
    const float* attn_e = (const float*)d_in[7];

    float* ret1 = (float*)d_out;                     // N*128, also node_out accum
    float* ret2 = ret1 + (size_t)NN * OUT_F;         // E*128, also e_ft scratch

    char* wsp = (char*)d_ws;
    float* ft     = (float*)wsp; wsp += (size_t)NN * OUT_F * 4;   // 25.6 MB
    float* a1buf  = (float*)wsp; wsp += (size_t)NN * HH * 4;
    float* a2buf  = (float*)wsp; wsp += (size_t)NN * HH * 4;
    float* logits = (float*)wsp; wsp += (size_t)EE * HH * 4;      // 12.8 MB
    unsigned* mkey = (unsigned*)wsp; wsp += (size_t)NN * HH * 4;
    float* ssum   = (float*)wsp; wsp += (size_t)NN * HH * 4;
    unsigned short* Whp = (unsigned short*)wsp; wsp += 32768 * 2; // 64 KB
    unsigned short* Wlp = (unsigned short*)wsp; wsp += 32768 * 2;

    hipMemsetAsync(mkey, 0, (size_t)NN * HH * 4, stream);
    hipMemsetAsync(ssum, 0, (size_t)NN * HH * 4, stream);
    hipMemsetAsync(ret1, 0, (size_t)NN * OUT_F * 4, stream);

    k_prepw<<<128, 256, 0, stream>>>(W, Whp, Wlp);
    k_gemm<0><<<(NN + 63) / 64, 256, 0, stream>>>(nf, NN, Whp, Wlp,
            attn_l, attn_r, nullptr, nullptr, nullptr, nullptr,
            ft, a1buf, a2buf, nullptr);
    k_gemm<1><<<EE / 64, 256, 0, stream>>>(ef, EE, Whp, Wlp,
            attn_e, nullptr, src, dst, a1buf, a2buf,
            ret2, logits, nullptr, mkey);
    k_exp<<<(EE * HH) / 256, 256, 0, stream>>>(dst, logits, mkey, ssum);
    k_final<<<EE / 4, 256, 0, stream>>>(src, dst, ft, logits, ssum, ret2, ret1);
    k_elu1<<<(NN * OUT_F) / 256, 256, 0, stream>>>(ret1, ret1);
}

// Round 3
// 1175.253 us; speedup vs baseline: 5.7724x; 1.1712x over previous
//
#include <hip/hip_runtime.h>
#include <hip/hip_bf16.h>
#include <math.h>

#define NN    50000
#define EE    800000
#define IN_F  256
#define HH    4
#define DD    32
#define OUT_F 128
#define ALPHA 0.2f

typedef float f32x4 __attribute__((ext_vector_type(4)));
typedef short bf16x8 __attribute__((ext_vector_type(8)));

// ---- monotonic float<->uint key for atomicMax on floats ----
__device__ __forceinline__ unsigned fkey(float x) {
    unsigned b = __float_as_uint(x);
    return b ^ ((unsigned)((int)b >> 31) | 0x80000000u);
}
__device__ __forceinline__ float fdecode(unsigned k) {
    unsigned b = (k & 0x80000000u) ? (k ^ 0x80000000u) : ~k;
    return __uint_as_float(b);
}
__device__ __forceinline__ float elu_f(float x) { return x > 0.0f ? x : expm1f(x); }

__device__ __forceinline__ unsigned short f2bf(float x) {
    union { float f; unsigned u; } v; v.f = x;
    unsigned r = (v.u + 0x7FFFu + ((v.u >> 16) & 1u)) >> 16;
    return (unsigned short)r;
}
__device__ __forceinline__ float bf2f(unsigned short h) {
    union { unsigned u; float f; } v; v.u = ((unsigned)h) << 16; return v.f;
}

// Pack W (256x128 f32) into MFMA B-fragment order, split hi/lo bf16.
__global__ __launch_bounds__(256) void k_prepw(const float* __restrict__ W,
        unsigned short* __restrict__ Whp, unsigned short* __restrict__ Wlp) {
    int i = blockIdx.x * 256 + threadIdx.x;        // 32768 total
    int j = i & 7, lane = (i >> 3) & 63, cf = (i >> 9) & 7, t = i >> 12;
    int krow = 32 * t + 8 * (lane >> 4) + j;
    int col  = 16 * cf + (lane & 15);
    float x = W[krow * OUT_F + col];
    unsigned short h = f2bf(x);
    unsigned short lo = f2bf(x - bf2f(h));
    Whp[i] = h; Wlp[i] = lo;
}

// Fused GEMM (64 rows x 128 cols, K=256) + attention-dot epilogue.
template <int MODE>
__global__ __launch_bounds__(256) void k_gemm(const float* __restrict__ X, int M,
        const unsigned short* __restrict__ Whp, const unsigned short* __restrict__ Wlp,
        const float* __restrict__ av0, const float* __restrict__ av1,
        const int* __restrict__ src, const int* __restrict__ dst,
        const float* __restrict__ a1, const float* __restrict__ a2,
        float* __restrict__ Y, float* __restrict__ o1, float* __restrict__ o2,
        unsigned* __restrict__ mkey) {
    __shared__ unsigned short Ah[64 * 256];   // 32 KB, XOR-swizzled
    __shared__ unsigned short Al[64 * 256];   // 32 KB

    const int tid = threadIdx.x;
    const int w = tid >> 6;          // wave = head
    const int l = tid & 63;
    const int base = blockIdx.x * 64;

    bf16x8 Bh[8][2], Bl[8][2];
    #pragma unroll
    for (int t = 0; t < 8; ++t)
        #pragma unroll
        for (int c = 0; c < 2; ++c) {
            size_t off = ((size_t)((t * 8) + (w * 2 + c)) * 64 + l) * 8;
            Bh[t][c] = *(const bf16x8*)(Whp + off);
            Bl[t][c] = *(const bf16x8*)(Wlp + off);
        }

    #pragma unroll
    for (int it = 0; it < 8; ++it) {
        int chunk = it * 256 + tid;            // 0..2047
        int rl = chunk >> 5;
        int c0 = (chunk & 31) * 8;
        int gr = base + rl; if (gr > M - 1) gr = M - 1;
        const float* p = X + (size_t)gr * IN_F + c0;
        float4 u0 = *(const float4*)(p);
        float4 u1 = *(const float4*)(p + 4);
        unsigned short h[8], lo[8];
        float xs[8] = {u0.x, u0.y, u0.z, u0.w, u1.x, u1.y, u1.z, u1.w};
        #pragma unroll
        for (int k = 0; k < 8; ++k) {
            h[k] = f2bf(xs[k]);
            lo[k] = f2bf(xs[k] - bf2f(h[k]));
        }
        unsigned ba = (unsigned)(rl * 512 + c0 * 2) ^ (unsigned)((rl & 7) << 4);
        *(bf16x8*)((char*)Ah + ba) = *(const bf16x8*)h;
        *(bf16x8*)((char*)Al + ba) = *(const bf16x8*)lo;
    }
    __syncthreads();

    f32x4 acc[4][2];
    #pragma unroll
    for (int rf = 0; rf < 4; ++rf)
        #pragma unroll
        for (int c = 0; c < 2; ++c)
            acc[rf][c] = (f32x4){0.f, 0.f, 0.f, 0.f};

    #pragma unroll
    for (int rf = 0; rf < 4; ++rf) {
        const int row = rf * 16 + (l & 15);
        #pragma unroll
        for (int t = 0; t < 8; ++t) {
            unsigned ba = (unsigned)(row * 512 + (32 * t + 8 * (l >> 4)) * 2)
                        ^ (unsigned)((row & 7) << 4);
            bf16x8 ah = *(const bf16x8*)((const char*)Ah + ba);
            bf16x8 al = *(const bf16x8*)((const char*)Al + ba);
            #pragma unroll
            for (int c = 0; c < 2; ++c) {
                acc[rf][c] = __builtin_amdgcn_mfma_f32_16x16x32_bf16(ah, Bh[t][c], acc[rf][c], 0, 0, 0);
                acc[rf][c] = __builtin_amdgcn_mfma_f32_16x16x32_bf16(al, Bh[t][c], acc[rf][c], 0, 0, 0);
                acc[rf][c] = __builtin_amdgcn_mfma_f32_16x16x32_bf16(ah, Bl[t][c], acc[rf][c], 0, 0, 0);
            }
        }
    }

    #pragma unroll
    for (int rf = 0; rf < 4; ++rf)
        #pragma unroll
        for (int c = 0; c < 2; ++c)
            #pragma unroll
            for (int r = 0; r < 4; ++r) {
                int grow = base + rf * 16 + (l >> 4) * 4 + r;
                if (grow < M)
                    Y[(size_t)grow * OUT_F + w * 32 + c * 16 + (l & 15)] = acc[rf][c][r];
            }

    const float b0 = av0[w * DD + (l & 15)];
    const float b1 = av0[w * DD + 16 + (l & 15)];
    float c0v = 0.f, c1v = 0.f;
    if (MODE == 0) { c0v = av1[w * DD + (l & 15)]; c1v = av1[w * DD + 16 + (l & 15)]; }

    #pragma unroll
    for (int rf = 0; rf < 4; ++rf) {
        float p[4], q[4];
        #pragma unroll
        for (int r = 0; r < 4; ++r) {
            p[r] = acc[rf][0][r] * b0 + acc[rf][1][r] * b1;
            q[r] = (MODE == 0) ? (acc[rf][0][r] * c0v + acc[rf][1][r] * c1v) : 0.f;
        }
        #pragma unroll
        for (int o = 1; o <= 8; o <<= 1)
            #pragma unroll
            for (int r = 0; r < 4; ++r) {
                p[r] += __shfl_xor(p[r], o);
                if (MODE == 0) q[r] += __shfl_xor(q[r], o);
            }
        if ((l & 15) == 0) {
            int rbase = rf * 16 + (l >> 4) * 4;
            #pragma unroll
            for (int r = 0; r < 4; ++r) {
                int grow = base + rbase + r;
                if (MODE == 0) {
                    if (grow < M) { o1[(size_t)grow * HH + w] = p[r]; o2[(size_t)grow * HH + w] = q[r]; }
                } else {
                    int s = src[grow], t2 = dst[grow];
                    float lg = a1[(size_t)s * HH + w] + a2[(size_t)t2 * HH + w] + p[r];
                    lg = fmaxf(lg, ALPHA * lg);
                    o1[(size_t)w * EE + grow] = lg;
                    atomicMax(&mkey[t2 * HH + w], fkey(lg));
                }
            }
        }
    }
}

// ex = exp(logit - m[dst]); ssum[dst] += ex   (logits layout [H][E], in-place)
__global__ __launch_bounds__(256) void k_exp(const int* __restrict__ dst,
        float* __restrict__ logits, const unsigned* __restrict__ mkey,
        float* __restrict__ ssum) {
    const int i = blockIdx.x * blockDim.x + threadIdx.x;
    if (i >= EE * HH) return;
    const int h = i / EE, e = i - h * EE;
    const int t = dst[e];
    float ex = expf(logits[i] - fdecode(mkey[t * HH + h]));
    logits[i] = ex;
    atomicAdd(&ssum[t * HH + h], ex);
}

// ---- CSR build: histogram, scan, scatter ----
__global__ __launch_bounds__(256) void k_hist(const int* __restrict__ dst,
        int* __restrict__ hist) {
    int i = blockIdx.x * 256 + threadIdx.x;
    if (i < EE) atomicAdd(&hist[dst[i]], 1);
}

// single-block exclusive scan of hist[NN] -> rowptr + cursor copy
__global__ __launch_bounds__(1024) void k_scan(const int* __restrict__ hist,
        int* __restrict__ rowptr, int* __restrict__ cursor) {
    __shared__ int part[1024];
    const int t = threadIdx.x;
    const int CH = (NN + 1023) / 1024;        // 49
    const int b = t * CH;
    int s = 0;
    for (int i = 0; i < CH; ++i) {
        int idx = b + i;
        if (idx < NN) s += hist[idx];
    }
    part[t] = s;
    __syncthreads();
    int total = s;
    for (int o = 1; o < 1024; o <<= 1) {
        int u = (t >= o) ? part[t - o] : 0;
        __syncthreads();
        part[t] += u;
        __syncthreads();
    }
    int run = part[t] - total;                // exclusive base for this thread
    for (int i = 0; i < CH; ++i) {
        int idx = b + i;
        if (idx < NN) {
            rowptr[idx] = run;
            cursor[idx] = run;
            run += hist[idx];
        }
    }
}

__global__ __launch_bounds__(256) void k_scatter(const int* __restrict__ dst,
        int* __restrict__ cursor, int* __restrict__ order) {
    int i = blockIdx.x * 256 + threadIdx.x;
    if (i < EE) {
        int pos = atomicAdd(&cursor[dst[i]], 1);
        order[pos] = i;
    }
}

// One wave per node: walk CSR edge list, a = ex/ssum, f = (e_ft+ft[src])*a,
// ret2[e] = elu(f) in place, acc += f, ret1[n] = elu(acc). No atomics.
__global__ __launch_bounds__(256) void k_agg(const int* __restrict__ order,
        const int* __restrict__ rowptr, const int* __restrict__ hist,
        const int* __restrict__ src, const float* __restrict__ ft,
        const float* __restrict__ ex, const float* __restrict__ ssum,
        float* __restrict__ ret2, float* __restrict__ ret1) {
    const int wave = threadIdx.x >> 6;
    const int lane = threadIdx.x & 63;
    const int n = blockIdx.x * 4 + wave;
    if (n >= NN) return;
    const int beg = rowptr[n];
    const int g   = hist[n];
    const int c0  = lane * 2;
    const int h   = lane >> 4;
    const float inv_s = __frcp_rn(ssum[n * HH + h]);   // unused if g==0

    float acc0 = 0.f, acc1 = 0.f;
    int e = (g > 0) ? order[beg] : 0;
    for (int i = 0; i < g; ++i) {
        int e_next = (i + 1 < g) ? order[beg + i + 1] : 0;
        const int s = src[e];
        const float a = ex[(size_t)h * EE + e] * inv_s;
        float2 ev = *(const float2*)(ret2 + (size_t)e * OUT_F + c0);
        float2 fv = *(const float2*)(ft + (size_t)s * OUT_F + c0);
        float f0 = (ev.x + fv.x) * a;
        float f1 = (ev.y + fv.y) * a;
        acc0 += f0; acc1 += f1;
        *(float2*)(ret2 + (size_t)e * OUT_F + c0) = make_float2(elu_f(f0), elu_f(f1));
        e = e_next;
    }
    const size_t o = (size_t)n * OUT_F + c0;
    ret1[o]     = elu_f(acc0);
    ret1[o + 1] = elu_f(acc1);
}

extern "C" void kernel_launch(void* const* d_in, const int* in_sizes, int n_in,
                              void* d_out, int out_size, void* d_ws, size_t ws_size,
                              hipStream_t stream) {
    const float* nf     = (const float*)d_in[0];
    const float* ef     = (const float*)d_in[1];
    const int*   src    = (const int*)d_in[2];
    const int*   dst    = (const int*)d_in[3];
    const float* W      = (const float*)d_in[4];
    const float* attn_l = (const float*)d_in[5];
    const float* attn_r = (const float*)d_in[6];
    const float* attn_e = (const float*)d_in[7];

    float* ret1 = (float*)d_out;                     // N*128
    float* ret2 = ret1 + (size_t)NN * OUT_F;         // E*128, also e_ft scratch

    char* wsp = (char*)d_ws;
    auto take = [&](size_t bytes) { char* p = wsp; wsp += (bytes + 511) & ~size_t(511); return p; };
    float* ft     = (float*)take((size_t)NN * OUT_F * 4);   // 25.6 MB
    float* a1buf  = (float*)take((size_t)NN * HH * 4);
    float* a2buf  = (float*)take((size_t)NN * HH * 4);
    float* logits = (float*)take((size_t)EE * HH * 4);      // 12.8 MB (becomes ex)
    unsigned* mkey = (unsigned*)take((size_t)NN * HH * 4);
    float* ssum   = (float*)take((size_t)NN * HH * 4);
    unsigned short* Whp = (unsigned short*)take(32768 * 2);
    unsigned short* Wlp = (unsigned short*)take(32768 * 2);
    int* hist   = (int*)take((size_t)NN * 4);
    int* rowptr = (int*)take((size_t)NN * 4);
    int* cursor = (int*)take((size_t)NN * 4);
    int* order  = (int*)take((size_t)EE * 4);               // 3.2 MB

    hipMemsetAsync(mkey, 0, (size_t)NN * HH * 4, stream);
    hipMemsetAsync(ssum, 0, (size_t)NN * HH * 4, stream);
    hipMemsetAsync(hist, 0, (size_t)NN * 4, stream);

    k_prepw<<<128, 256, 0, stream>>>(W, Whp, Wlp);
    k_hist<<<(EE + 255) / 256, 256, 0, stream>>>(dst, hist);
    k_scan<<<1, 1024, 0, stream>>>(hist, rowptr, cursor);
    k_scatter<<<(EE + 255) / 256, 256, 0, stream>>>(dst, cursor, order);

    k_gemm<0><<<(NN + 63) / 64, 256, 0, stream>>>(nf, NN, Whp, Wlp,
            attn_l, attn_r, nullptr, nullptr, nullptr, nullptr,
            ft, a1buf, a2buf, nullptr);
    k_gemm<1><<<EE / 64, 256, 0, stream>>>(ef, EE, Whp, Wlp,
            attn_e, nullptr, src, dst, a1buf, a2buf,
            ret2, logits, nullptr, mkey);
    k_exp<<<(EE * HH) / 256, 256, 0, stream>>>(dst, logits, mkey, ssum);
    k_agg<<<(NN + 3) / 4, 256, 0, stream>>>(order, rowptr, hist, src, ft,
            logits, ssum, ret2, ret1);
}

// Round 4
// 1072.349 us; speedup vs baseline: 6.3263x; 1.0960x over previous
//
#include <hip/hip_runtime.h>
#include <hip/hip_bf16.h>
#include <math.h>

#define NN    50000
#define EE    800000
#define IN_F  256
#define HH    4
#define DD    32
#define OUT_F 128
#define ALPHA 0.2f

typedef float f32x4 __attribute__((ext_vector_type(4)));
typedef short bf16x8 __attribute__((ext_vector_type(8)));

// ---- monotonic float<->uint key for atomicMax on floats ----
__device__ __forceinline__ unsigned fkey(float x) {
    unsigned b = __float_as_uint(x);
    return b ^ ((unsigned)((int)b >> 31) | 0x80000000u);
}
__device__ __forceinline__ float fdecode(unsigned k) {
    unsigned b = (k & 0x80000000u) ? (k ^ 0x80000000u) : ~k;
    return __uint_as_float(b);
}
__device__ __forceinline__ float elu_f(float x) { return x > 0.0f ? x : expm1f(x); }

__device__ __forceinline__ unsigned short f2bf(float x) {
    union { float f; unsigned u; } v; v.f = x;
    unsigned r = (v.u + 0x7FFFu + ((v.u >> 16) & 1u)) >> 16;
    return (unsigned short)r;
}
__device__ __forceinline__ float bf2f(unsigned short h) {
    union { unsigned u; float f; } v; v.u = ((unsigned)h) << 16; return v.f;
}

// Pack W (256x128 f32) into MFMA B-fragment order, split hi/lo bf16.
// idx = ((t*8 + cf)*64 + lane)*8 + j  ->  W[32t + 8*(lane>>4) + j][16cf + (lane&15)]
__global__ __launch_bounds__(256) void k_prepw(const float* __restrict__ W,
        unsigned short* __restrict__ Whp, unsigned short* __restrict__ Wlp) {
    int i = blockIdx.x * 256 + threadIdx.x;        // 32768 total
    int j = i & 7, lane = (i >> 3) & 63, cf = (i >> 9) & 7, t = i >> 12;
    int krow = 32 * t + 8 * (lane >> 4) + j;
    int col  = 16 * cf + (lane & 15);
    float x = W[krow * OUT_F + col];
    unsigned short h = f2bf(x);
    unsigned short lo = f2bf(x - bf2f(h));
    Whp[i] = h; Wlp[i] = lo;
}

// K-chunked fused GEMM (64 rows x 128 cols, K=256 in 4 chunks of 64) +
// attention-dot epilogue. Double-buffered LDS, 4 blocks/CU.
// MODE 0: node -> Y=ft, o1=a1, o2=a2.  MODE 1: edge -> Y=e_ft, o1=logits[H][E].
template <int MODE>
__global__ __launch_bounds__(256, 4) void k_gemm(const float* __restrict__ X, int M,
        const unsigned short* __restrict__ Whp, const unsigned short* __restrict__ Wlp,
        const float* __restrict__ av0, const float* __restrict__ av1,
        const int* __restrict__ src, const int* __restrict__ dst,
        const float* __restrict__ a1, const float* __restrict__ a2,
        float* __restrict__ Y, float* __restrict__ o1, float* __restrict__ o2,
        unsigned* __restrict__ mkey) {
    __shared__ unsigned short Asw[2][2][64 * 64];   // [dbuf][hi/lo][swizzled 8KB plane]

    const int tid = threadIdx.x;
    const int w = tid >> 6;          // wave = head
    const int l = tid & 63;
    const int base = blockIdx.x * 64;

    // staging geometry: thread -> (row, 16-float column group)
    const int srow = tid >> 2;                 // 0..63
    const int scg  = tid & 3;                  // 0..3
    int gr = base + srow; if (gr > M - 1) gr = M - 1;
    const float* xp = X + (size_t)gr * IN_F + scg * 16;

    float4 xs[4];
    #pragma unroll
    for (int q = 0; q < 4; ++q) xs[q] = *(const float4*)(xp + q * 4);

    auto cvtwrite = [&](int buf) {
        unsigned short h[16], lo[16];
        const float* xf = (const float*)xs;
        #pragma unroll
        for (int k = 0; k < 16; ++k) {
            h[k]  = f2bf(xf[k]);
            lo[k] = f2bf(xf[k] - bf2f(h[k]));
        }
        const unsigned sw = (unsigned)((srow & 7) << 4);
        const unsigned b0 = (unsigned)(srow * 128 + scg * 32) ^ sw;
        const unsigned b1 = (unsigned)(srow * 128 + scg * 32 + 16) ^ sw;
        char* ph = (char*)&Asw[buf][0][0];
        char* pl = (char*)&Asw[buf][1][0];
        *(bf16x8*)(ph + b0) = *(const bf16x8*)(h);
        *(bf16x8*)(ph + b1) = *(const bf16x8*)(h + 8);
        *(bf16x8*)(pl + b0) = *(const bf16x8*)(lo);
        *(bf16x8*)(pl + b1) = *(const bf16x8*)(lo + 8);
    };
    cvtwrite(0);

    f32x4 acc[4][2];
    #pragma unroll
    for (int rf = 0; rf < 4; ++rf)
        #pragma unroll
        for (int cf = 0; cf < 2; ++cf)
            acc[rf][cf] = (f32x4){0.f, 0.f, 0.f, 0.f};

    #pragma unroll
    for (int c = 0; c < 4; ++c) {
        __syncthreads();
        // B fragments for this chunk (L2-resident packed W) — issued first
        bf16x8 Bh[2][2], Bl[2][2];
        #pragma unroll
        for (int ks = 0; ks < 2; ++ks)
            #pragma unroll
            for (int cf = 0; cf < 2; ++cf) {
                size_t off = ((size_t)((c * 2 + ks) * 8 + (w * 2 + cf)) * 64 + l) * 8;
                Bh[ks][cf] = *(const bf16x8*)(Whp + off);
                Bl[ks][cf] = *(const bf16x8*)(Wlp + off);
            }
        // prefetch next A chunk (latency hides under MFMA below)
        if (c < 3) {
            #pragma unroll
            for (int q = 0; q < 4; ++q)
                xs[q] = *(const float4*)(xp + (c + 1) * 64 + q * 4);
        }
        // MFMA over this chunk
        const char* ph = (const char*)&Asw[c & 1][0][0];
        const char* pl = (const char*)&Asw[c & 1][1][0];
        #pragma unroll
        for (int rf = 0; rf < 4; ++rf) {
            const int row = rf * 16 + (l & 15);
            const unsigned sw = (unsigned)((row & 7) << 4);
            #pragma unroll
            for (int ks = 0; ks < 2; ++ks) {
                const unsigned ba = (unsigned)(row * 128 + ks * 64 + (l >> 4) * 16) ^ sw;
                bf16x8 ah = *(const bf16x8*)(ph + ba);
                bf16x8 al = *(const bf16x8*)(pl + ba);
                #pragma unroll
                for (int cf = 0; cf < 2; ++cf) {
                    acc[rf][cf] = __builtin_amdgcn_mfma_f32_16x16x32_bf16(ah, Bh[ks][cf], acc[rf][cf], 0, 0, 0);
                    acc[rf][cf] = __builtin_amdgcn_mfma_f32_16x16x32_bf16(al, Bh[ks][cf], acc[rf][cf], 0, 0, 0);
                    acc[rf][cf] = __builtin_amdgcn_mfma_f32_16x16x32_bf16(ah, Bl[ks][cf], acc[rf][cf], 0, 0, 0);
                }
            }
        }
        // write next chunk into the idle buffer (no barrier needed here)
        if (c < 3) cvtwrite((c + 1) & 1);
    }

    // ---- store Y (ft / e_ft) ----
    #pragma unroll
    for (int rf = 0; rf < 4; ++rf)
        #pragma unroll
        for (int cf = 0; cf < 2; ++cf)
            #pragma unroll
            for (int r = 0; r < 4; ++r) {
                int grow = base + rf * 16 + (l >> 4) * 4 + r;
                if (grow < M)
                    Y[(size_t)grow * OUT_F + w * 32 + cf * 16 + (l & 15)] = acc[rf][cf][r];
            }

    // ---- attention-dot epilogue (wave w == head w) ----
    const float b0 = av0[w * DD + (l & 15)];
    const float b1 = av0[w * DD + 16 + (l & 15)];
    float c0v = 0.f, c1v = 0.f;
    if (MODE == 0) { c0v = av1[w * DD + (l & 15)]; c1v = av1[w * DD + 16 + (l & 15)]; }

    #pragma unroll
    for (int rf = 0; rf < 4; ++rf) {
        float p[4], q[4];
        #pragma unroll
        for (int r = 0; r < 4; ++r) {
            p[r] = acc[rf][0][r] * b0 + acc[rf][1][r] * b1;
            q[r] = (MODE == 0) ? (acc[rf][0][r] * c0v + acc[rf][1][r] * c1v) : 0.f;
        }
        #pragma unroll
        for (int o = 1; o <= 8; o <<= 1)
            #pragma unroll
            for (int r = 0; r < 4; ++r) {
                p[r] += __shfl_xor(p[r], o);
                if (MODE == 0) q[r] += __shfl_xor(q[r], o);
            }
        if ((l & 15) == 0) {
            int rbase = rf * 16 + (l >> 4) * 4;
            #pragma unroll
            for (int r = 0; r < 4; ++r) {
                int grow = base + rbase + r;
                if (MODE == 0) {
                    if (grow < M) { o1[(size_t)grow * HH + w] = p[r]; o2[(size_t)grow * HH + w] = q[r]; }
                } else {
                    int s = src[grow], t2 = dst[grow];
                    float lg = a1[(size_t)s * HH + w] + a2[(size_t)t2 * HH + w] + p[r];
                    lg = fmaxf(lg, ALPHA * lg);
                    o1[(size_t)w * EE + grow] = lg;
                    atomicMax(&mkey[t2 * HH + w], fkey(lg));
                }
            }
        }
    }
}

// ex = exp(logit - m[dst]); ssum[dst] += ex   (logits layout [H][E], in-place)
__global__ __launch_bounds__(256) void k_exp(const int* __restrict__ dst,
        float* __restrict__ logits, const unsigned* __restrict__ mkey,
        float* __restrict__ ssum) {
    const int i = blockIdx.x * blockDim.x + threadIdx.x;
    if (i >= EE * HH) return;
    const int h = i / EE, e = i - h * EE;
    const int t = dst[e];
    float ex = expf(logits[i] - fdecode(mkey[t * HH + h]));
    logits[i] = ex;
    atomicAdd(&ssum[t * HH + h], ex);
}

// ---- CSR build: histogram, scan, scatter ----
__global__ __launch_bounds__(256) void k_hist(const int* __restrict__ dst,
        int* __restrict__ hist) {
    int i = blockIdx.x * 256 + threadIdx.x;
    if (i < EE) atomicAdd(&hist[dst[i]], 1);
}

__global__ __launch_bounds__(1024) void k_scan(const int* __restrict__ hist,
        int* __restrict__ rowptr, int* __restrict__ cursor) {
    __shared__ int part[1024];
    const int t = threadIdx.x;
    const int CH = (NN + 1023) / 1024;        // 49
    const int b = t * CH;
    int s = 0;
    for (int i = 0; i < CH; ++i) {
        int idx = b + i;
        if (idx < NN) s += hist[idx];
    }
    part[t] = s;
    __syncthreads();
    int total = s;
    for (int o = 1; o < 1024; o <<= 1) {
        int u = (t >= o) ? part[t - o] : 0;
        __syncthreads();
        part[t] += u;
        __syncthreads();
    }
    int run = part[t] - total;
    for (int i = 0; i < CH; ++i) {
        int idx = b + i;
        if (idx < NN) {
            rowptr[idx] = run;
            cursor[idx] = run;
            run += hist[idx];
        }
    }
}

__global__ __launch_bounds__(256) void k_scatter(const int* __restrict__ dst,
        int* __restrict__ cursor, int* __restrict__ order) {
    int i = blockIdx.x * 256 + threadIdx.x;
    if (i < EE) {
        int pos = atomicAdd(&cursor[dst[i]], 1);
        order[pos] = i;
    }
}

// One wave per node: walk CSR edge list, a = ex/ssum, f = (e_ft+ft[src])*a,
// ret2[e] = elu(f) in place, acc += f, ret1[n] = elu(acc). No atomics.
__global__ __launch_bounds__(256) void k_agg(const int* __restrict__ order,
        const int* __restrict__ rowptr, const int* __restrict__ hist,
        const int* __restrict__ src, const float* __restrict__ ft,
        const float* __restrict__ ex, const float* __restrict__ ssum,
        float* __restrict__ ret2, float* __restrict__ ret1) {
    const int wave = threadIdx.x >> 6;
    const int lane = threadIdx.x & 63;
    const int n = blockIdx.x * 4 + wave;
    if (n >= NN) return;
    const int beg = rowptr[n];
    const int g   = hist[n];
    const int c0  = lane * 2;
    const int h   = lane >> 4;
    const float inv_s = __frcp_rn(ssum[n * HH + h]);

    float acc0 = 0.f, acc1 = 0.f;
    int e = (g > 0) ? order[beg] : 0;
    for (int i = 0; i < g; ++i) {
        int e_next = (i + 1 < g) ? order[beg + i + 1] : 0;
        const int s = src[e];
        const float a = ex[(size_t)h * EE + e] * inv_s;
        float2 ev = *(const float2*)(ret2 + (size_t)e * OUT_F + c0);
        float2 fv = *(const float2*)(ft + (size_t)s * OUT_F + c0);
        float f0 = (ev.x + fv.x) * a;
        float f1 = (ev.y + fv.y) * a;
        acc0 += f0; acc1 += f1;
        *(float2*)(ret2 + (size_t)e * OUT_F + c0) = make_float2(elu_f(f0), elu_f(f1));
        e = e_next;
    }
    const size_t o = (size_t)n * OUT_F + c0;
    ret1[o]     = elu_f(acc0);
    ret1[o + 1] = elu_f(acc1);
}

extern "C" void kernel_launch(void* const* d_in, const int* in_sizes, int n_in,
                              void* d_out, int out_size, void* d_ws, size_t ws_size,
                              hipStream_t stream) {
    const float* nf     = (const float*)d_in[0];
    const float* ef     = (const float*)d_in[1];
    const int*   src    = (const int*)d_in[2];
    const int*   dst    = (const int*)d_in[3];
    const float* W      = (const float*)d_in[4];
    const float* attn_l = (const float*)d_in[5];
    const float* attn_r = (const float*)d_in[6];
    const float* attn_e = (const float*)d_in[7];

    float* ret1 = (float*)d_out;                     // N*128
    float* ret2 = ret1 + (size_t)NN * OUT_F;         // E*128, also e_ft scratch

    char* wsp = (char*)d_ws;
    auto take = [&](size_t bytes) { char* p = wsp; wsp += (bytes + 511) & ~size_t(511); return p; };
    float* ft     = (float*)take((size_t)NN * OUT_F * 4);   // 25.6 MB
    float* a1buf  = (float*)take((size_t)NN * HH * 4);
    float* a2buf  = (float*)take((size_t)NN * HH * 4);
    float* logits = (float*)take((size_t)EE * HH * 4);      // 12.8 MB (becomes ex)
    unsigned* mkey = (unsigned*)take((size_t)NN * HH * 4);
    float* ssum   = (float*)take((size_t)NN * HH * 4);
    unsigned short* Whp = (unsigned short*)take(32768 * 2);
    unsigned short* Wlp = (unsigned short*)take(32768 * 2);
    int* hist   = (int*)take((size_t)NN * 4);
    int* rowptr = (int*)take((size_t)NN * 4);
    int* cursor = (int*)take((size_t)NN * 4);
    int* order  = (int*)take((size_t)EE * 4);               // 3.2 MB

    hipMemsetAsync(mkey, 0, (size_t)NN * HH * 4, stream);
    hipMemsetAsync(ssum, 0, (size_t)NN * HH * 4, stream);
    hipMemsetAsync(hist, 0, (size_t)NN * 4, stream);

    k_prepw<<<128, 256, 0, stream>>>(W, Whp, Wlp);
    k_hist<<<(EE + 255) / 256, 256, 0, stream>>>(dst, hist);
    k_scan<<<1, 1024, 0, stream>>>(hist, rowptr, cursor);
    k_scatter<<<(EE + 255) / 256, 256, 0, stream>>>(dst, cursor, order);

    k_gemm<0><<<(NN + 63) / 64, 256, 0, stream>>>(nf, NN, Whp, Wlp,
            attn_l, attn_r, nullptr, nullptr, nullptr, nullptr,
            ft, a1buf, a2buf, nullptr);
    k_gemm<1><<<EE / 64, 256, 0, stream>>>(ef, EE, Whp, Wlp,
            attn_e, nullptr, src, dst, a1buf, a2buf,
            ret2, logits, nullptr, mkey);
    k_exp<<<(EE * HH) / 256, 256, 0, stream>>>(dst, logits, mkey, ssum);
    k_agg<<<(NN + 3) / 4, 256, 0, stream>>>(order, rowptr, hist, src, ft,
            logits, ssum, ret2, ret1);
}

// Round 5
// 939.878 us; speedup vs baseline: 7.2180x; 1.1409x over previous
//
#include <hip/hip_runtime.h>
#include <hip/hip_bf16.h>
#include <math.h>

#define NN    50000
#define EE    800000
#define IN_F  256
#define HH    4
#define DD    32
#define OUT_F 128
#define ALPHA 0.2f

typedef float f32x4 __attribute__((ext_vector_type(4)));
typedef short bf16x8 __attribute__((ext_vector_type(8)));

__device__ __forceinline__ float elu_f(float x) { return x > 0.0f ? x : expm1f(x); }

__device__ __forceinline__ unsigned short f2bf(float x) {
    union { float f; unsigned u; } v; v.f = x;
    unsigned r = (v.u + 0x7FFFu + ((v.u >> 16) & 1u)) >> 16;
    return (unsigned short)r;
}
__device__ __forceinline__ float bf2f(unsigned short h) {
    union { unsigned u; float f; } v; v.u = ((unsigned)h) << 16; return v.f;
}

// Pack W (256x128 f32) into MFMA B-fragment order, split hi/lo bf16.
__global__ __launch_bounds__(256) void k_prepw(const float* __restrict__ W,
        unsigned short* __restrict__ Whp, unsigned short* __restrict__ Wlp) {
    int i = blockIdx.x * 256 + threadIdx.x;        // 32768 total
    int j = i & 7, lane = (i >> 3) & 63, cf = (i >> 9) & 7, t = i >> 12;
    int krow = 32 * t + 8 * (lane >> 4) + j;
    int col  = 16 * cf + (lane & 15);
    float x = W[krow * OUT_F + col];
    unsigned short h = f2bf(x);
    unsigned short lo = f2bf(x - bf2f(h));
    Whp[i] = h; Wlp[i] = lo;
}

// K-chunked fused GEMM (64 rows x 128 cols, K=256 in 4 chunks of 64).
// MODE 0: node -> Y=ft, o1=a1, o2=a2.
// MODE 1: edge -> Y=e_ft(ret2), o1=exbuf[H][E] (=exp(leaky(logit))), ssum atomicAdd.
template <int MODE>
__global__ __launch_bounds__(256, 4) void k_gemm(const float* __restrict__ X, int M,
        const unsigned short* __restrict__ Whp, const unsigned short* __restrict__ Wlp,
        const float* __restrict__ av0, const float* __restrict__ av1,
        const int* __restrict__ src, const int* __restrict__ dst,
        const float* __restrict__ a1, const float* __restrict__ a2,
        float* __restrict__ Y, float* __restrict__ o1, float* __restrict__ o2,
        float* __restrict__ ssum) {
    __shared__ unsigned short Asw[2][2][64 * 64];   // [dbuf][hi/lo][8KB swizzled plane]

    const int tid = threadIdx.x;
    const int w = tid >> 6;          // wave = head
    const int l = tid & 63;
    const int base = blockIdx.x * 64;

    const int srow = tid >> 2;                 // 0..63
    const int scg  = tid & 3;                  // 0..3
    int gr = base + srow; if (gr > M - 1) gr = M - 1;
    const float* xp = X + (size_t)gr * IN_F + scg * 16;

    float4 xs[4];
    #pragma unroll
    for (int q = 0; q < 4; ++q) xs[q] = *(const float4*)(xp + q * 4);

    auto cvtwrite = [&](int buf) {
        unsigned short h[16], lo[16];
        const float* xf = (const float*)xs;
        #pragma unroll
        for (int k = 0; k < 16; ++k) {
            h[k]  = f2bf(xf[k]);
            lo[k] = f2bf(xf[k] - bf2f(h[k]));
        }
        const unsigned sw = (unsigned)((srow & 7) << 4);
        const unsigned b0 = (unsigned)(srow * 128 + scg * 32) ^ sw;
        const unsigned b1 = (unsigned)(srow * 128 + scg * 32 + 16) ^ sw;
        char* ph = (char*)&Asw[buf][0][0];
        char* pl = (char*)&Asw[buf][1][0];
        *(bf16x8*)(ph + b0) = *(const bf16x8*)(h);
        *(bf16x8*)(ph + b1) = *(const bf16x8*)(h + 8);
        *(bf16x8*)(pl + b0) = *(const bf16x8*)(lo);
        *(bf16x8*)(pl + b1) = *(const bf16x8*)(lo + 8);
    };
    cvtwrite(0);

    f32x4 acc[4][2];
    #pragma unroll
    for (int rf = 0; rf < 4; ++rf)
        #pragma unroll
        for (int cf = 0; cf < 2; ++cf)
            acc[rf][cf] = (f32x4){0.f, 0.f, 0.f, 0.f};

    #pragma unroll
    for (int c = 0; c < 4; ++c) {
        __syncthreads();
        bf16x8 Bh[2][2], Bl[2][2];
        #pragma unroll
        for (int ks = 0; ks < 2; ++ks)
            #pragma unroll
            for (int cf = 0; cf < 2; ++cf) {
                size_t off = ((size_t)((c * 2 + ks) * 8 + (w * 2 + cf)) * 64 + l) * 8;
                Bh[ks][cf] = *(const bf16x8*)(Whp + off);
                Bl[ks][cf] = *(const bf16x8*)(Wlp + off);
            }
        if (c < 3) {
            #pragma unroll
            for (int q = 0; q < 4; ++q)
                xs[q] = *(const float4*)(xp + (c + 1) * 64 + q * 4);
        }
        const char* ph = (const char*)&Asw[c & 1][0][0];
        const char* pl = (const char*)&Asw[c & 1][1][0];
        #pragma unroll
        for (int rf = 0; rf < 4; ++rf) {
            const int row = rf * 16 + (l & 15);
            const unsigned sw = (unsigned)((row & 7) << 4);
            #pragma unroll
            for (int ks = 0; ks < 2; ++ks) {
                const unsigned ba = (unsigned)(row * 128 + ks * 64 + (l >> 4) * 16) ^ sw;
                bf16x8 ah = *(const bf16x8*)(ph + ba);
                bf16x8 al = *(const bf16x8*)(pl + ba);
                #pragma unroll
                for (int cf = 0; cf < 2; ++cf) {
                    acc[rf][cf] = __builtin_amdgcn_mfma_f32_16x16x32_bf16(ah, Bh[ks][cf], acc[rf][cf], 0, 0, 0);
                    acc[rf][cf] = __builtin_amdgcn_mfma_f32_16x16x32_bf16(al, Bh[ks][cf], acc[rf][cf], 0, 0, 0);
                    acc[rf][cf] = __builtin_amdgcn_mfma_f32_16x16x32_bf16(ah, Bl[ks][cf], acc[rf][cf], 0, 0, 0);
                }
            }
        }
        if (c < 3) cvtwrite((c + 1) & 1);
    }

    // ---- store Y (ft / e_ft) ----
    #pragma unroll
    for (int rf = 0; rf < 4; ++rf)
        #pragma unroll
        for (int cf = 0; cf < 2; ++cf)
            #pragma unroll
            for (int r = 0; r < 4; ++r) {
                int grow = base + rf * 16 + (l >> 4) * 4 + r;
                if (grow < M)
                    Y[(size_t)grow * OUT_F + w * 32 + cf * 16 + (l & 15)] = acc[rf][cf][r];
            }

    // ---- attention-dot epilogue (wave w == head w) ----
    const float b0 = av0[w * DD + (l & 15)];
    const float b1 = av0[w * DD + 16 + (l & 15)];
    float c0v = 0.f, c1v = 0.f;
    if (MODE == 0) { c0v = av1[w * DD + (l & 15)]; c1v = av1[w * DD + 16 + (l & 15)]; }

    #pragma unroll
    for (int rf = 0; rf < 4; ++rf) {
        float p[4], q[4];
        #pragma unroll
        for (int r = 0; r < 4; ++r) {
            p[r] = acc[rf][0][r] * b0 + acc[rf][1][r] * b1;
            q[r] = (MODE == 0) ? (acc[rf][0][r] * c0v + acc[rf][1][r] * c1v) : 0.f;
        }
        #pragma unroll
        for (int o = 1; o <= 8; o <<= 1)
            #pragma unroll
            for (int r = 0; r < 4; ++r) {
                p[r] += __shfl_xor(p[r], o);
                if (MODE == 0) q[r] += __shfl_xor(q[r], o);
            }
        if ((l & 15) == 0) {
            int rbase = rf * 16 + (l >> 4) * 4;
            #pragma unroll
            for (int r = 0; r < 4; ++r) {
                int grow = base + rbase + r;
                if (MODE == 0) {
                    if (grow < M) { o1[(size_t)grow * HH + w] = p[r]; o2[(size_t)grow * HH + w] = q[r]; }
                } else {
                    int s = src[grow], t2 = dst[grow];
                    float lg = a1[(size_t)s * HH + w] + a2[(size_t)t2 * HH + w] + p[r];
                    lg = fmaxf(lg, ALPHA * lg);          // leaky_relu
                    float exv = expf(lg);                // no max-shift (|lg|max ~70 << 88)
                    o1[(size_t)w * EE + grow] = exv;
                    atomicAdd(&ssum[t2 * HH + w], exv);
                }
            }
        }
    }
}

// ---- CSR build: histogram, scan, scatter ----
__global__ __launch_bounds__(256) void k_hist(const int* __restrict__ dst,
        int* __restrict__ hist) {
    int i = blockIdx.x * 256 + threadIdx.x;
    if (i < EE) atomicAdd(&hist[dst[i]], 1);
}

__global__ __launch_bounds__(1024) void k_scan(const int* __restrict__ hist,
        int* __restrict__ rowptr, int* __restrict__ cursor) {
    __shared__ int part[1024];
    const int t = threadIdx.x;
    const int CH = (NN + 1023) / 1024;        // 49
    const int b = t * CH;
    int s = 0;
    for (int i = 0; i < CH; ++i) {
        int idx = b + i;
        if (idx < NN) s += hist[idx];
    }
    part[t] = s;
    __syncthreads();
    int total = s;
    for (int o = 1; o < 1024; o <<= 1) {
        int u = (t >= o) ? part[t - o] : 0;
        __syncthreads();
        part[t] += u;
        __syncthreads();
    }
    int run = part[t] - total;
    for (int i = 0; i < CH; ++i) {
        int idx = b + i;
        if (idx < NN) {
            rowptr[idx] = run;
            cursor[idx] = run;
            run += hist[idx];
        }
    }
}

__global__ __launch_bounds__(256) void k_scatter(const int* __restrict__ dst,
        int* __restrict__ cursor, int* __restrict__ order) {
    int i = blockIdx.x * 256 + threadIdx.x;
    if (i < EE) {
        int pos = atomicAdd(&cursor[dst[i]], 1);
        order[pos] = i;
    }
}

// Edge-centric aggregation over dst-sorted order[]. Block = 64 sorted edges,
// wave w owns contiguous rows [16w, 16w+16). Per row: a = ex/ssum,
// f = (e_ft + ft[src])*a, ret2[e] = elu(f) in place, segment-accumulate f.
// Interior segments -> plain float2 store to node_out; boundary-crossing
// segments -> atomicAdd onto zeroed node_out.
__global__ __launch_bounds__(256, 8) void k_agg2(const int* __restrict__ order,
        const int* __restrict__ src, const int* __restrict__ dst,
        const float* __restrict__ ft, const float* __restrict__ ex,
        const float* __restrict__ ssum, float* __restrict__ ret2,
        float* __restrict__ node_out) {
    __shared__ int eL[64], sL[64], dL[64];
    __shared__ int sent[2];
    const int tid = threadIdx.x;
    const int base = blockIdx.x * 64;
    if (tid < 64) {
        int e = order[base + tid];
        eL[tid] = e;
        sL[tid] = src[e];
        dL[tid] = dst[e];
    } else if (tid == 64) {
        sent[0] = (blockIdx.x > 0) ? dst[order[base - 1]] : -1;
    } else if (tid == 65) {
        sent[1] = (base + 64 < EE) ? dst[order[base + 64]] : -1;
    }
    __syncthreads();

    const int w = tid >> 6, l = tid & 63;
    const int W0 = w * 16, W1 = W0 + 15;
    const int c0 = l * 2, h = l >> 4;

    const int dprev  = (W0 == 0)  ? sent[0] : dL[W0 - 1];
    const int dafter = (W1 == 63) ? sent[1] : dL[W1 + 1];

    float acc0 = 0.f, acc1 = 0.f;
    int dcur = dL[W0];
    bool touch_start = true;

    #pragma unroll 4
    for (int r = W0; r <= W1; ++r) {
        const int e = eL[r], s = sL[r], d = dL[r];
        if (d != dcur) {       // wave-uniform branch: flush completed run
            const size_t o = (size_t)dcur * OUT_F + c0;
            if (touch_start && dcur == dprev) {
                atomicAdd(&node_out[o], acc0);
                atomicAdd(&node_out[o + 1], acc1);
            } else {
                *(float2*)(node_out + o) = make_float2(acc0, acc1);
            }
            acc0 = acc1 = 0.f; dcur = d; touch_start = false;
        }
        const float a = ex[(size_t)h * EE + e] * __frcp_rn(ssum[d * HH + h]);
        float2 ev = *(const float2*)(ret2 + (size_t)e * OUT_F + c0);
        float2 fv = *(const float2*)(ft + (size_t)s * OUT_F + c0);
        float f0 = (ev.x + fv.x) * a;
        float f1 = (ev.y + fv.y) * a;
        acc0 += f0; acc1 += f1;
        *(float2*)(ret2 + (size_t)e * OUT_F + c0) = make_float2(elu_f(f0), elu_f(f1));
    }
    {
        const size_t o = (size_t)dcur * OUT_F + c0;
        const bool at = (touch_start && dcur == dprev) || (dcur == dafter);
        if (at) {
            atomicAdd(&node_out[o], acc0);
            atomicAdd(&node_out[o + 1], acc1);
        } else {
            *(float2*)(node_out + o) = make_float2(acc0, acc1);
        }
    }
}

__global__ __launch_bounds__(256) void k_elu1(const float* __restrict__ node_out,
        float* __restrict__ ret1) {
    const int i = blockIdx.x * blockDim.x + threadIdx.x;
    if (i < NN * OUT_F) ret1[i] = elu_f(node_out[i]);
}

extern "C" void kernel_launch(void* const* d_in, const int* in_sizes, int n_in,
                              void* d_out, int out_size, void* d_ws, size_t ws_size,
                              hipStream_t stream) {
    const float* nf     = (const float*)d_in[0];
    const float* ef     = (const float*)d_in[1];
    const int*   src    = (const int*)d_in[2];
    const int*   dst    = (const int*)d_in[3];
    const float* W      = (const float*)d_in[4];
    const float* attn_l = (const float*)d_in[5];
    const float* attn_r = (const float*)d_in[6];
    const float* attn_e = (const float*)d_in[7];

    float* ret1 = (float*)d_out;                     // N*128, node_out accum
    float* ret2 = ret1 + (size_t)NN * OUT_F;         // E*128, e_ft then elu(f)

    char* wsp = (char*)d_ws;
    auto take = [&](size_t bytes) { char* p = wsp; wsp += (bytes + 511) & ~size_t(511); return p; };
    float* ft     = (float*)take((size_t)NN * OUT_F * 4);   // 25.6 MB
    float* a1buf  = (float*)take((size_t)NN * HH * 4);
    float* a2buf  = (float*)take((size_t)NN * HH * 4);
    float* exbuf  = (float*)take((size_t)EE * HH * 4);      // 12.8 MB
    float* ssum   = (float*)take((size_t)NN * HH * 4);
    unsigned short* Whp = (unsigned short*)take(32768 * 2);
    unsigned short* Wlp = (unsigned short*)take(32768 * 2);
    int* hist   = (int*)take((size_t)NN * 4);
    int* rowptr = (int*)take((size_t)NN * 4);
    int* cursor = (int*)take((size_t)NN * 4);
    int* order  = (int*)take((size_t)EE * 4);               // 3.2 MB

    hipMemsetAsync(ssum, 0, (size_t)NN * HH * 4, stream);
    hipMemsetAsync(hist, 0, (size_t)NN * 4, stream);
    hipMemsetAsync(ret1, 0, (size_t)NN * OUT_F * 4, stream);

    k_prepw<<<128, 256, 0, stream>>>(W, Whp, Wlp);
    k_hist<<<(EE + 255) / 256, 256, 0, stream>>>(dst, hist);
    k_scan<<<1, 1024, 0, stream>>>(hist, rowptr, cursor);
    k_scatter<<<(EE + 255) / 256, 256, 0, stream>>>(dst, cursor, order);

    k_gemm<0><<<(NN + 63) / 64, 256, 0, stream>>>(nf, NN, Whp, Wlp,
            attn_l, attn_r, nullptr, nullptr, nullptr, nullptr,
            ft, a1buf, a2buf, nullptr);
    k_gemm<1><<<EE / 64, 256, 0, stream>>>(ef, EE, Whp, Wlp,
            attn_e, nullptr, src, dst, a1buf, a2buf,
            ret2, exbuf, nullptr, ssum);

    k_agg2<<<EE / 64, 256, 0, stream>>>(order, src, dst, ft, exbuf, ssum,
                                        ret2, ret1);
    k_elu1<<<(NN * OUT_F) / 256, 256, 0, stream>>>(ret1, ret1);
}

// Round 6
// 811.844 us; speedup vs baseline: 8.3563x; 1.1577x over previous
//
#include <hip/hip_runtime.h>
#include <hip/hip_bf16.h>
#include <math.h>

#define NN    50000
#define EE    800000
#define IN_F  256
#define HH    4
#define DD    32
#define OUT_F 128
#define ALPHA 0.2f

typedef float f32x4 __attribute__((ext_vector_type(4)));
typedef short bf16x8 __attribute__((ext_vector_type(8)));

__device__ __forceinline__ float elu_f(float x) { return x > 0.0f ? x : expm1f(x); }

__device__ __forceinline__ unsigned short f2bf(float x) {
    union { float f; unsigned u; } v; v.f = x;
    unsigned r = (v.u + 0x7FFFu + ((v.u >> 16) & 1u)) >> 16;
    return (unsigned short)r;
}
__device__ __forceinline__ float bf2f(unsigned short h) {
    union { unsigned u; float f; } v; v.u = ((unsigned)h) << 16; return v.f;
}

// Pack W (256x128 f32) into MFMA B-fragment order, split hi/lo bf16.
__global__ __launch_bounds__(256) void k_prepw(const float* __restrict__ W,
        unsigned short* __restrict__ Whp, unsigned short* __restrict__ Wlp) {
    int i = blockIdx.x * 256 + threadIdx.x;        // 32768 total
    int j = i & 7, lane = (i >> 3) & 63, cf = (i >> 9) & 7, t = i >> 12;
    int krow = 32 * t + 8 * (lane >> 4) + j;
    int col  = 16 * cf + (lane & 15);
    float x = W[krow * OUT_F + col];
    unsigned short h = f2bf(x);
    unsigned short lo = f2bf(x - bf2f(h));
    Whp[i] = h; Wlp[i] = lo;
}

// K-chunked fused GEMM (64 rows x 128 cols, K=256 in 4 chunks of 64).
// MODE 0: node -> Yf=ft(f32), o1=a1, o2=a2.
// MODE 1: edge -> e_ft to Yh(bf16) if EFB else Yf(f32=ret2);
//         o1=exq[E][H] = exp(leaky(logit)); ssum atomicAdd. Full-wave epilogue.
template <int MODE, bool EFB>
__global__ __launch_bounds__(256, 4) void k_gemm(const float* __restrict__ X, int M,
        const unsigned short* __restrict__ Whp, const unsigned short* __restrict__ Wlp,
        const float* __restrict__ av0, const float* __restrict__ av1,
        const int* __restrict__ src, const int* __restrict__ dst,
        const float* __restrict__ a1, const float* __restrict__ a2,
        float* __restrict__ Yf, unsigned short* __restrict__ Yh,
        float* __restrict__ o1, float* __restrict__ o2,
        float* __restrict__ ssum) {
    __shared__ unsigned short Asw[2][2][64 * 64];   // [dbuf][hi/lo][8KB swizzled]
    __shared__ float p_lds[4][64];
    __shared__ float q_lds[4][64];

    const int tid = threadIdx.x;
    const int w = tid >> 6;          // wave = head
    const int l = tid & 63;
    const int base = blockIdx.x * 64;

    const int srow = tid >> 2;                 // 0..63
    const int scg  = tid & 3;                  // 0..3
    int gr = base + srow; if (gr > M - 1) gr = M - 1;
    const float* xp = X + (size_t)gr * IN_F + scg * 16;

    float4 xs[4];
    #pragma unroll
    for (int q = 0; q < 4; ++q) xs[q] = *(const float4*)(xp + q * 4);

    auto cvtwrite = [&](int buf) {
        unsigned short h[16], lo[16];
        const float* xf = (const float*)xs;
        #pragma unroll
        for (int k = 0; k < 16; ++k) {
            h[k]  = f2bf(xf[k]);
            lo[k] = f2bf(xf[k] - bf2f(h[k]));
        }
        const unsigned sw = (unsigned)((srow & 7) << 4);
        const unsigned b0 = (unsigned)(srow * 128 + scg * 32) ^ sw;
        const unsigned b1 = (unsigned)(srow * 128 + scg * 32 + 16) ^ sw;
        char* ph = (char*)&Asw[buf][0][0];
        char* pl = (char*)&Asw[buf][1][0];
        *(bf16x8*)(ph + b0) = *(const bf16x8*)(h);
        *(bf16x8*)(ph + b1) = *(const bf16x8*)(h + 8);
        *(bf16x8*)(pl + b0) = *(const bf16x8*)(lo);
        *(bf16x8*)(pl + b1) = *(const bf16x8*)(lo + 8);
    };
    cvtwrite(0);

    f32x4 acc[4][2];
    #pragma unroll
    for (int rf = 0; rf < 4; ++rf)
        #pragma unroll
        for (int cf = 0; cf < 2; ++cf)
            acc[rf][cf] = (f32x4){0.f, 0.f, 0.f, 0.f};

    #pragma unroll
    for (int c = 0; c < 4; ++c) {
        __syncthreads();
        // issue next A chunk loads FIRST (HBM latency hides under B-load+MFMA)
        if (c < 3) {
            #pragma unroll
            for (int q = 0; q < 4; ++q)
                xs[q] = *(const float4*)(xp + (c + 1) * 64 + q * 4);
        }
        bf16x8 Bh[2][2], Bl[2][2];
        #pragma unroll
        for (int ks = 0; ks < 2; ++ks)
            #pragma unroll
            for (int cf = 0; cf < 2; ++cf) {
                size_t off = ((size_t)((c * 2 + ks) * 8 + (w * 2 + cf)) * 64 + l) * 8;
                Bh[ks][cf] = *(const bf16x8*)(Whp + off);
                Bl[ks][cf] = *(const bf16x8*)(Wlp + off);
            }
        const char* ph = (const char*)&Asw[c & 1][0][0];
        const char* pl = (const char*)&Asw[c & 1][1][0];
        #pragma unroll
        for (int rf = 0; rf < 4; ++rf) {
            const int row = rf * 16 + (l & 15);
            const unsigned sw = (unsigned)((row & 7) << 4);
            #pragma unroll
            for (int ks = 0; ks < 2; ++ks) {
                const unsigned ba = (unsigned)(row * 128 + ks * 64 + (l >> 4) * 16) ^ sw;
                bf16x8 ah = *(const bf16x8*)(ph + ba);
                bf16x8 al = *(const bf16x8*)(pl + ba);
                #pragma unroll
                for (int cf = 0; cf < 2; ++cf) {
                    acc[rf][cf] = __builtin_amdgcn_mfma_f32_16x16x32_bf16(ah, Bh[ks][cf], acc[rf][cf], 0, 0, 0);
                    acc[rf][cf] = __builtin_amdgcn_mfma_f32_16x16x32_bf16(al, Bh[ks][cf], acc[rf][cf], 0, 0, 0);
                    acc[rf][cf] = __builtin_amdgcn_mfma_f32_16x16x32_bf16(ah, Bl[ks][cf], acc[rf][cf], 0, 0, 0);
                }
            }
        }
        if (c < 3) cvtwrite((c + 1) & 1);
    }

    // ---- store ft / e_ft ----
    #pragma unroll
    for (int rf = 0; rf < 4; ++rf)
        #pragma unroll
        for (int cf = 0; cf < 2; ++cf)
            #pragma unroll
            for (int r = 0; r < 4; ++r) {
                int grow = base + rf * 16 + (l >> 4) * 4 + r;
                size_t oidx = (size_t)grow * OUT_F + w * 32 + cf * 16 + (l & 15);
                if (MODE == 0) {
                    if (grow < M) Yf[oidx] = acc[rf][cf][r];
                } else if (EFB) {
                    Yh[oidx] = f2bf(acc[rf][cf][r]);
                } else {
                    Yf[oidx] = acc[rf][cf][r];
                }
            }

    // ---- attention dots: reduce, stage via LDS, full-wave epilogue ----
    const float b0 = av0[w * DD + (l & 15)];
    const float b1 = av0[w * DD + 16 + (l & 15)];
    float c0v = 0.f, c1v = 0.f;
    if (MODE == 0) { c0v = av1[w * DD + (l & 15)]; c1v = av1[w * DD + 16 + (l & 15)]; }

    float pv[4][4], qv[4][4];
    #pragma unroll
    for (int rf = 0; rf < 4; ++rf)
        #pragma unroll
        for (int r = 0; r < 4; ++r) {
            pv[rf][r] = acc[rf][0][r] * b0 + acc[rf][1][r] * b1;
            if (MODE == 0) qv[rf][r] = acc[rf][0][r] * c0v + acc[rf][1][r] * c1v;
        }
    #pragma unroll
    for (int o = 1; o <= 8; o <<= 1)
        #pragma unroll
        for (int rf = 0; rf < 4; ++rf)
            #pragma unroll
            for (int r = 0; r < 4; ++r) {
                pv[rf][r] += __shfl_xor(pv[rf][r], o);
                if (MODE == 0) qv[rf][r] += __shfl_xor(qv[rf][r], o);
            }
    if ((l & 15) == 0) {
        const int hi = l >> 4;
        #pragma unroll
        for (int rf = 0; rf < 4; ++rf)
            #pragma unroll
            for (int r = 0; r < 4; ++r) {
                p_lds[w][rf * 16 + hi * 4 + r] = pv[rf][r];
                if (MODE == 0) q_lds[w][rf * 16 + hi * 4 + r] = qv[rf][r];
            }
    }
    __syncthreads();

    const int grow = base + l;
    if (MODE == 0) {
        if (grow < M) {
            o1[(size_t)grow * HH + w] = p_lds[w][l];
            o2[(size_t)grow * HH + w] = q_lds[w][l];
        }
    } else {
        const int s = src[grow], t2 = dst[grow];
        float lg = p_lds[w][l] + a1[(size_t)s * HH + w] + a2[(size_t)t2 * HH + w];
        lg = fmaxf(lg, ALPHA * lg);          // leaky_relu
        float exv = expf(lg);                // no max-shift (|lg|max ~70 << 88)
        o1[(size_t)grow * HH + w] = exv;     // [E][H]
        atomicAdd(&ssum[t2 * HH + w], exv);
    }
}

// ---- CSR build: histogram, scan, scatter ----
__global__ __launch_bounds__(256) void k_hist(const int* __restrict__ dst,
        int* __restrict__ hist) {
    int i = blockIdx.x * 256 + threadIdx.x;
    if (i < EE) atomicAdd(&hist[dst[i]], 1);
}

__global__ __launch_bounds__(1024) void k_scan(const int* __restrict__ hist,
        int* __restrict__ rowptr, int* __restrict__ cursor) {
    __shared__ int part[1024];
    const int t = threadIdx.x;
    const int CH = (NN + 1023) / 1024;        // 49
    const int b = t * CH;
    int s = 0;
    for (int i = 0; i < CH; ++i) {
        int idx = b + i;
        if (idx < NN) s += hist[idx];
    }
    part[t] = s;
    __syncthreads();
    int total = s;
    for (int o = 1; o < 1024; o <<= 1) {
        int u = (t >= o) ? part[t - o] : 0;
        __syncthreads();
        part[t] += u;
        __syncthreads();
    }
    int run = part[t] - total;
    for (int i = 0; i < CH; ++i) {
        int idx = b + i;
        if (idx < NN) {
            rowptr[idx] = run;
            cursor[idx] = run;
            run += hist[idx];
        }
    }
}

__global__ __launch_bounds__(256) void k_scatter(const int* __restrict__ dst,
        int* __restrict__ cursor, int* __restrict__ order) {
    int i = blockIdx.x * 256 + threadIdx.x;
    if (i < EE) {
        int pos = atomicAdd(&cursor[dst[i]], 1);
        order[pos] = i;
    }
}

// Edge-centric aggregation over dst-sorted order[]. Block = 64 sorted edges,
// wave w owns rows [16w,16w+16). e_ft read from bf16 (EFB) or fp32-in-ret2.
// ret2 gets elu(f) (write-only when EFB). Interior segments -> plain store;
// boundary segments -> atomicAdd onto zeroed node_out.
template <bool EFB>
__global__ __launch_bounds__(256, 8) void k_agg2(const int* __restrict__ order,
        const int* __restrict__ src, const int* __restrict__ dst,
        const float* __restrict__ ft, const float* __restrict__ exq,
        const float* __restrict__ ssum, const unsigned short* __restrict__ eftb,
        float* __restrict__ ret2, float* __restrict__ node_out) {
    __shared__ int eL[64], sL[64], dL[64];
    __shared__ int sent[2];
    const int tid = threadIdx.x;
    const int base = blockIdx.x * 64;
    if (tid < 64) {
        int e = order[base + tid];
        eL[tid] = e;
        sL[tid] = src[e];
        dL[tid] = dst[e];
    } else if (tid == 64) {
        sent[0] = (blockIdx.x > 0) ? dst[order[base - 1]] : -1;
    } else if (tid == 65) {
        sent[1] = (base + 64 < EE) ? dst[order[base + 64]] : -1;
    }
    __syncthreads();

    const int w = tid >> 6, l = tid & 63;
    const int W0 = w * 16, W1 = W0 + 15;
    const int c0 = l * 2, h = l >> 4;

    const int dprev  = (W0 == 0)  ? sent[0] : dL[W0 - 1];
    const int dafter = (W1 == 63) ? sent[1] : dL[W1 + 1];

    float acc0 = 0.f, acc1 = 0.f;
    int dcur = dL[W0];
    bool touch_start = true;

    #pragma unroll 4
    for (int r = W0; r <= W1; ++r) {
        const int e = eL[r], s = sL[r], d = dL[r];
        if (d != dcur) {       // wave-uniform: flush completed run
            const size_t o = (size_t)dcur * OUT_F + c0;
            if (touch_start && dcur == dprev) {
                atomicAdd(&node_out[o], acc0);
                atomicAdd(&node_out[o + 1], acc1);
            } else {
                *(float2*)(node_out + o) = make_float2(acc0, acc1);
            }
            acc0 = acc1 = 0.f; dcur = d; touch_start = false;
        }
        const float a = exq[(size_t)e * HH + h] * __frcp_rn(ssum[d * HH + h]);
        float e0, e1;
        if (EFB) {
            ushort2 ev = *(const ushort2*)(eftb + (size_t)e * OUT_F + c0);
            e0 = bf2f(ev.x); e1 = bf2f(ev.y);
        } else {
            float2 ev = *(const float2*)(ret2 + (size_t)e * OUT_F + c0);
            e0 = ev.x; e1 = ev.y;
        }
        float2 fv = *(const float2*)(ft + (size_t)s * OUT_F + c0);
        float f0 = (e0 + fv.x) * a;
        float f1 = (e1 + fv.y) * a;
        acc0 += f0; acc1 += f1;
        *(float2*)(ret2 + (size_t)e * OUT_F + c0) = make_float2(elu_f(f0), elu_f(f1));
    }
    {
        const size_t o = (size_t)dcur * OUT_F + c0;
        const bool at = (touch_start && dcur == dprev) || (dcur == dafter);
        if (at) {
            atomicAdd(&node_out[o], acc0);
            atomicAdd(&node_out[o + 1], acc1);
        } else {
            *(float2*)(node_out + o) = make_float2(acc0, acc1);
        }
    }
}

__global__ __launch_bounds__(256) void k_elu1(const float4* __restrict__ node_out,
        float4* __restrict__ ret1) {
    const int i = blockIdx.x * blockDim.x + threadIdx.x;
    if (i < NN * OUT_F / 4) {
        float4 v = node_out[i];
        ret1[i] = make_float4(elu_f(v.x), elu_f(v.y), elu_f(v.z), elu_f(v.w));
    }
}

extern "C" void kernel_launch(void* const* d_in, const int* in_sizes, int n_in,
                              void* d_out, int out_size, void* d_ws, size_t ws_size,
                              hipStream_t stream) {
    const float* nf     = (const float*)d_in[0];
    const float* ef     = (const float*)d_in[1];
    const int*   src    = (const int*)d_in[2];
    const int*   dst    = (const int*)d_in[3];
    const float* W      = (const float*)d_in[4];
    const float* attn_l = (const float*)d_in[5];
    const float* attn_r = (const float*)d_in[6];
    const float* attn_e = (const float*)d_in[7];

    float* ret1 = (float*)d_out;                     // N*128, node_out accum
    float* ret2 = ret1 + (size_t)NN * OUT_F;         // E*128 output

    char* wsp = (char*)d_ws;
    auto take = [&](size_t bytes) { char* p = wsp; wsp += (bytes + 511) & ~size_t(511); return p; };
    float* ft     = (float*)take((size_t)NN * OUT_F * 4);   // 25.6 MB
    float* a1buf  = (float*)take((size_t)NN * HH * 4);
    float* a2buf  = (float*)take((size_t)NN * HH * 4);
    float* exq    = (float*)take((size_t)EE * HH * 4);      // 12.8 MB, [E][H]
    float* ssum   = (float*)take((size_t)NN * HH * 4);
    unsigned short* Whp = (unsigned short*)take(32768 * 2);
    unsigned short* Wlp = (unsigned short*)take(32768 * 2);
    int* hist   = (int*)take((size_t)NN * 4);
    int* rowptr = (int*)take((size_t)NN * 4);
    int* cursor = (int*)take((size_t)NN * 4);
    int* order  = (int*)take((size_t)EE * 4);               // 3.2 MB

    const size_t eft_bytes = (size_t)EE * OUT_F * 2;        // 204.8 MB
    const size_t used = (size_t)(wsp - (char*)d_ws);
    const bool efb = (used + eft_bytes + 1024) <= ws_size;
    unsigned short* eftb = efb ? (unsigned short*)take(eft_bytes) : nullptr;

    hipMemsetAsync(ssum, 0, (size_t)NN * HH * 4, stream);
    hipMemsetAsync(hist, 0, (size_t)NN * 4, stream);
    hipMemsetAsync(ret1, 0, (size_t)NN * OUT_F * 4, stream);

    k_prepw<<<128, 256, 0, stream>>>(W, Whp, Wlp);
    k_hist<<<(EE + 255) / 256, 256, 0, stream>>>(dst, hist);
    k_scan<<<1, 1024, 0, stream>>>(hist, rowptr, cursor);
    k_scatter<<<(EE + 255) / 256, 256, 0, stream>>>(dst, cursor, order);

    k_gemm<0, false><<<(NN + 63) / 64, 256, 0, stream>>>(nf, NN, Whp, Wlp,
            attn_l, attn_r, nullptr, nullptr, nullptr, nullptr,
            ft, nullptr, a1buf, a2buf, nullptr);

    if (efb) {
        k_gemm<1, true><<<EE / 64, 256, 0, stream>>>(ef, EE, Whp, Wlp,
                attn_e, nullptr, src, dst, a1buf, a2buf,
                nullptr, eftb, exq, nullptr, ssum);
        k_agg2<true><<<EE / 64, 256, 0, stream>>>(order, src, dst, ft, exq,
                ssum, eftb, ret2, ret1);
    } else {
        k_gemm<1, false><<<EE / 64, 256, 0, stream>>>(ef, EE, Whp, Wlp,
                attn_e, nullptr, src, dst, a1buf, a2buf,
                ret2, nullptr, exq, nullptr, ssum);
        k_agg2<false><<<EE / 64, 256, 0, stream>>>(order, src, dst, ft, exq,
                ssum, nullptr, ret2, ret1);
    }
    k_elu1<<<(NN * OUT_F / 4 + 255) / 256, 256, 0, stream>>>(
            (const float4*)ret1, (float4*)ret1);
}

// Round 7
// 756.032 us; speedup vs baseline: 8.9732x; 1.0738x over previous
//
#include <hip/hip_runtime.h>
#include <hip/hip_bf16.h>
#include <math.h>

#define NN    50000
#define EE    800000
#define IN_F  256
#define HH    4
#define DD    32
#define OUT_F 128
#define ALPHA 0.2f

typedef float f32x4 __attribute__((ext_vector_type(4)));
typedef short bf16x8 __attribute__((ext_vector_type(8)));

__device__ __forceinline__ float elu_f(float x) { return x > 0.0f ? x : expm1f(x); }

__device__ __forceinline__ unsigned short f2bf(float x) {
    union { float f; unsigned u; } v; v.f = x;
    unsigned r = (v.u + 0x7FFFu + ((v.u >> 16) & 1u)) >> 16;
    return (unsigned short)r;
}
__device__ __forceinline__ float bf2f(unsigned short h) {
    union { unsigned u; float f; } v; v.u = ((unsigned)h) << 16; return v.f;
}

// Fused setup: blocks [0,128) pack W into MFMA B-frag order (hi/lo bf16);
// [128,3253) histogram dst; [3253,3449) zero ssum; [3449,9699) zero ret1.
#define PREP_B 128
#define HIST_B 3125
#define SSUM_B 196
#define RET1_B 6250
__global__ __launch_bounds__(256) void k_setup(const float* __restrict__ W,
        unsigned short* __restrict__ Whp, unsigned short* __restrict__ Wlp,
        const int* __restrict__ dst, int* __restrict__ hist,
        float4* __restrict__ ssum4, float4* __restrict__ ret14) {
    const int b = blockIdx.x, tid = threadIdx.x;
    if (b < PREP_B) {
        int i = b * 256 + tid;                 // 32768 total
        int j = i & 7, lane = (i >> 3) & 63, cf = (i >> 9) & 7, t = i >> 12;
        int krow = 32 * t + 8 * (lane >> 4) + j;
        int col  = 16 * cf + (lane & 15);
        float x = W[krow * OUT_F + col];
        unsigned short h = f2bf(x);
        Whp[i] = h;
        Wlp[i] = f2bf(x - bf2f(h));
    } else if (b < PREP_B + HIST_B) {
        int i = (b - PREP_B) * 256 + tid;      // exactly EE
        atomicAdd(&hist[dst[i]], 1);
    } else if (b < PREP_B + HIST_B + SSUM_B) {
        int i = (b - PREP_B - HIST_B) * 256 + tid;
        if (i < NN * HH / 4) ssum4[i] = make_float4(0.f, 0.f, 0.f, 0.f);
    } else {
        int i = (b - PREP_B - HIST_B - SSUM_B) * 256 + tid;   // exactly NN*OUT_F/4
        ret14[i] = make_float4(0.f, 0.f, 0.f, 0.f);
    }
}

// K-chunked fused GEMM (64 rows x 128 cols, K=256 in 4 chunks of 64).
// MODE 0: node -> Yh=ft(bf16), o1=a1, o2=a2.
// MODE 1: edge -> Yh=e_ft(bf16), o1=exq[E][H]=exp(leaky(logit)), ssum atomicAdd.
// Edge epilogue gathers (src/dst -> a1/a2) hoisted to kernel start so their
// dependent-latency chain hides under the MFMA main loop.
template <int MODE>
__global__ __launch_bounds__(256, 4) void k_gemm(const float* __restrict__ X, int M,
        const unsigned short* __restrict__ Whp, const unsigned short* __restrict__ Wlp,
        const float* __restrict__ av0, const float* __restrict__ av1,
        const int* __restrict__ src, const int* __restrict__ dst,
        const float* __restrict__ a1, const float* __restrict__ a2,
        unsigned short* __restrict__ Yh,
        float* __restrict__ o1, float* __restrict__ o2,
        float* __restrict__ ssum) {
    __shared__ unsigned short Asw[2][2][64 * 64];   // [dbuf][hi/lo][8KB swizzled]
    __shared__ float p_lds[4][64];
    __shared__ float q_lds[4][64];

    const int tid = threadIdx.x;
    const int w = tid >> 6;          // wave = head
    const int l = tid & 63;
    const int base = blockIdx.x * 64;

    // hoisted edge metadata loads (independent; issue first)
    int s_e = 0, t_e = 0;
    if (MODE == 1) { s_e = src[base + l]; t_e = dst[base + l]; }

    const int srow = tid >> 2;                 // 0..63
    const int scg  = tid & 3;                  // 0..3
    int gr = base + srow; if (gr > M - 1) gr = M - 1;
    const float* xp = X + (size_t)gr * IN_F + scg * 16;

    float4 xs[4];
    #pragma unroll
    for (int q = 0; q < 4; ++q) xs[q] = *(const float4*)(xp + q * 4);

    auto cvtwrite = [&](int buf) {
        unsigned short h[16], lo[16];
        const float* xf = (const float*)xs;
        #pragma unroll
        for (int k = 0; k < 16; ++k) {
            h[k]  = f2bf(xf[k]);
            lo[k] = f2bf(xf[k] - bf2f(h[k]));
        }
        const unsigned sw = (unsigned)((srow & 7) << 4);
        const unsigned b0 = (unsigned)(srow * 128 + scg * 32) ^ sw;
        const unsigned b1 = (unsigned)(srow * 128 + scg * 32 + 16) ^ sw;
        char* ph = (char*)&Asw[buf][0][0];
        char* pl = (char*)&Asw[buf][1][0];
        *(bf16x8*)(ph + b0) = *(const bf16x8*)(h);
        *(bf16x8*)(ph + b1) = *(const bf16x8*)(h + 8);
        *(bf16x8*)(pl + b0) = *(const bf16x8*)(lo);
        *(bf16x8*)(pl + b1) = *(const bf16x8*)(lo + 8);
    };
    cvtwrite(0);

    // dependent gathers: s_e/t_e have arrived by now; loads fly under chunk 0
    float a1v = 0.f, a2v = 0.f;
    if (MODE == 1) {
        a1v = a1[(size_t)s_e * HH + w];
        a2v = a2[(size_t)t_e * HH + w];
    }

    f32x4 acc[4][2];
    #pragma unroll
    for (int rf = 0; rf < 4; ++rf)
        #pragma unroll
        for (int cf = 0; cf < 2; ++cf)
            acc[rf][cf] = (f32x4){0.f, 0.f, 0.f, 0.f};

    #pragma unroll
    for (int c = 0; c < 4; ++c) {
        __syncthreads();
        // issue next A chunk loads FIRST (HBM latency hides under B-load+MFMA)
        if (c < 3) {
            #pragma unroll
            for (int q = 0; q < 4; ++q)
                xs[q] = *(const float4*)(xp + (c + 1) * 64 + q * 4);
        }
        bf16x8 Bh[2][2], Bl[2][2];
        #pragma unroll
        for (int ks = 0; ks < 2; ++ks)
            #pragma unroll
            for (int cf = 0; cf < 2; ++cf) {
                size_t off = ((size_t)((c * 2 + ks) * 8 + (w * 2 + cf)) * 64 + l) * 8;
                Bh[ks][cf] = *(const bf16x8*)(Whp + off);
                Bl[ks][cf] = *(const bf16x8*)(Wlp + off);
            }
        const char* ph = (const char*)&Asw[c & 1][0][0];
        const char* pl = (const char*)&Asw[c & 1][1][0];
        #pragma unroll
        for (int rf = 0; rf < 4; ++rf) {
            const int row = rf * 16 + (l & 15);
            const unsigned sw = (unsigned)((row & 7) << 4);
            #pragma unroll
            for (int ks = 0; ks < 2; ++ks) {
                const unsigned ba = (unsigned)(row * 128 + ks * 64 + (l >> 4) * 16) ^ sw;
                bf16x8 ah = *(const bf16x8*)(ph + ba);
                bf16x8 al = *(const bf16x8*)(pl + ba);
                #pragma unroll
                for (int cf = 0; cf < 2; ++cf) {
                    acc[rf][cf] = __builtin_amdgcn_mfma_f32_16x16x32_bf16(ah, Bh[ks][cf], acc[rf][cf], 0, 0, 0);
                    acc[rf][cf] = __builtin_amdgcn_mfma_f32_16x16x32_bf16(al, Bh[ks][cf], acc[rf][cf], 0, 0, 0);
                    acc[rf][cf] = __builtin_amdgcn_mfma_f32_16x16x32_bf16(ah, Bl[ks][cf], acc[rf][cf], 0, 0, 0);
                }
            }
        }
        if (c < 3) cvtwrite((c + 1) & 1);
    }

    // ---- store ft / e_ft as bf16 ----
    #pragma unroll
    for (int rf = 0; rf < 4; ++rf)
        #pragma unroll
        for (int cf = 0; cf < 2; ++cf)
            #pragma unroll
            for (int r = 0; r < 4; ++r) {
                int grow = base + rf * 16 + (l >> 4) * 4 + r;
                if (MODE == 1 || grow < M)
                    Yh[(size_t)grow * OUT_F + w * 32 + cf * 16 + (l & 15)] =
                        f2bf(acc[rf][cf][r]);
            }

    // ---- attention dots: reduce, stage via LDS, full-wave epilogue ----
    const float b0 = av0[w * DD + (l & 15)];
    const float b1 = av0[w * DD + 16 + (l & 15)];
    float c0v = 0.f, c1v = 0.f;
    if (MODE == 0) { c0v = av1[w * DD + (l & 15)]; c1v = av1[w * DD + 16 + (l & 15)]; }

    float pv[4][4], qv[4][4];
    #pragma unroll
    for (int rf = 0; rf < 4; ++rf)
        #pragma unroll
        for (int r = 0; r < 4; ++r) {
            pv[rf][r] = acc[rf][0][r] * b0 + acc[rf][1][r] * b1;
            if (MODE == 0) qv[rf][r] = acc[rf][0][r] * c0v + acc[rf][1][r] * c1v;
        }
    #pragma unroll
    for (int o = 1; o <= 8; o <<= 1)
        #pragma unroll
        for (int rf = 0; rf < 4; ++rf)
            #pragma unroll
            for (int r = 0; r < 4; ++r) {
                pv[rf][r] += __shfl_xor(pv[rf][r], o);
                if (MODE == 0) qv[rf][r] += __shfl_xor(qv[rf][r], o);
            }
    if ((l & 15) == 0) {
        const int hi = l >> 4;
        #pragma unroll
        for (int rf = 0; rf < 4; ++rf)
            #pragma unroll
            for (int r = 0; r < 4; ++r) {
                p_lds[w][rf * 16 + hi * 4 + r] = pv[rf][r];
                if (MODE == 0) q_lds[w][rf * 16 + hi * 4 + r] = qv[rf][r];
            }
    }
    __syncthreads();

    const int grow = base + l;
    if (MODE == 0) {
        if (grow < M) {
            o1[(size_t)grow * HH + w] = p_lds[w][l];
            o2[(size_t)grow * HH + w] = q_lds[w][l];
        }
    } else {
        float lg = p_lds[w][l] + a1v + a2v;
        lg = fmaxf(lg, ALPHA * lg);          // leaky_relu
        float exv = expf(lg);                // no max-shift (|lg|max ~70 << 88)
        o1[(size_t)grow * HH + w] = exv;     // [E][H]
        atomicAdd(&ssum[t_e * HH + w], exv);
    }
}

// single-block exclusive scan of hist[NN] -> rowptr(cursor)
__global__ __launch_bounds__(1024) void k_scan(const int* __restrict__ hist,
        int* __restrict__ cursor) {
    __shared__ int part[1024];
    const int t = threadIdx.x;
    const int CH = (NN + 1023) / 1024;        // 49
    const int b = t * CH;
    int s = 0;
    for (int i = 0; i < CH; ++i) {
        int idx = b + i;
        if (idx < NN) s += hist[idx];
    }
    part[t] = s;
    __syncthreads();
    int total = s;
    for (int o = 1; o < 1024; o <<= 1) {
        int u = (t >= o) ? part[t - o] : 0;
        __syncthreads();
        part[t] += u;
        __syncthreads();
    }
    int run = part[t] - total;
    for (int i = 0; i < CH; ++i) {
        int idx = b + i;
        if (idx < NN) {
            cursor[idx] = run;
            run += hist[idx];
        }
    }
}

__global__ __launch_bounds__(256) void k_scatter(const int* __restrict__ dst,
        int* __restrict__ cursor, int* __restrict__ order) {
    int i = blockIdx.x * 256 + threadIdx.x;
    if (i < EE) {
        int pos = atomicAdd(&cursor[dst[i]], 1);
        order[pos] = i;
    }
}

// Edge-centric aggregation over dst-sorted order[]. Block = 64 sorted edges,
// wave w owns rows [16w,16w+16). e_ft and ft read as bf16. ret2 gets elu(f)
// (write-only). Interior segments -> plain store; boundary -> atomicAdd.
__global__ __launch_bounds__(256, 8) void k_agg2(const int* __restrict__ order,
        const int* __restrict__ src, const int* __restrict__ dst,
        const unsigned short* __restrict__ ftb, const float* __restrict__ exq,
        const float* __restrict__ ssum, const unsigned short* __restrict__ eftb,
        float* __restrict__ ret2, float* __restrict__ node_out) {
    __shared__ int eL[64], sL[64], dL[64];
    __shared__ int sent[2];
    const int tid = threadIdx.x;
    const int base = blockIdx.x * 64;
    if (tid < 64) {
        int e = order[base + tid];
        eL[tid] = e;
        sL[tid] = src[e];
        dL[tid] = dst[e];
    } else if (tid == 64) {
        sent[0] = (blockIdx.x > 0) ? dst[order[base - 1]] : -1;
    } else if (tid == 65) {
        sent[1] = (base + 64 < EE) ? dst[order[base + 64]] : -1;
    }
    __syncthreads();

    const int w = tid >> 6, l = tid & 63;
    const int W0 = w * 16, W1 = W0 + 15;
    const int c0 = l * 2, h = l >> 4;

    const int dprev  = (W0 == 0)  ? sent[0] : dL[W0 - 1];
    const int dafter = (W1 == 63) ? sent[1] : dL[W1 + 1];

    float acc0 = 0.f, acc1 = 0.f;
    int dcur = dL[W0];
    bool touch_start = true;

    #pragma unroll 4
    for (int r = W0; r <= W1; ++r) {
        const int e = eL[r], s = sL[r], d = dL[r];
        if (d != dcur) {       // wave-uniform: flush completed run
            const size_t o = (size_t)dcur * OUT_F + c0;
            if (touch_start && dcur == dprev) {
                atomicAdd(&node_out[o], acc0);
                atomicAdd(&node_out[o + 1], acc1);
            } else {
                *(float2*)(node_out + o) = make_float2(acc0, acc1);
            }
            acc0 = acc1 = 0.f; dcur = d; touch_start = false;
        }
        const float a = exq[(size_t)e * HH + h] * __frcp_rn(ssum[d * HH + h]);
        ushort2 ev = *(const ushort2*)(eftb + (size_t)e * OUT_F + c0);
        ushort2 fv = *(const ushort2*)(ftb + (size_t)s * OUT_F + c0);
        float f0 = (bf2f(ev.x) + bf2f(fv.x)) * a;
        float f1 = (bf2f(ev.y) + bf2f(fv.y)) * a;
        acc0 += f0; acc1 += f1;
        *(float2*)(ret2 + (size_t)e * OUT_F + c0) = make_float2(elu_f(f0), elu_f(f1));
    }
    {
        const size_t o = (size_t)dcur * OUT_F + c0;
        const bool at = (touch_start && dcur == dprev) || (dcur == dafter);
        if (at) {
            atomicAdd(&node_out[o], acc0);
            atomicAdd(&node_out[o + 1], acc1);
        } else {
            *(float2*)(node_out + o) = make_float2(acc0, acc1);
        }
    }
}

__global__ __launch_bounds__(256) void k_elu1(const float4* __restrict__ node_out,
        float4* __restrict__ ret1) {
    const int i = blockIdx.x * blockDim.x + threadIdx.x;
    if (i < NN * OUT_F / 4) {
        float4 v = node_out[i];
        ret1[i] = make_float4(elu_f(v.x), elu_f(v.y), elu_f(v.z), elu_f(v.w));
    }
}

extern "C" void kernel_launch(void* const* d_in, const int* in_sizes, int n_in,
                              void* d_out, int out_size, void* d_ws, size_t ws_size,
                              hipStream_t stream) {
    const float* nf     = (const float*)d_in[0];
    const float* ef     = (const float*)d_in[1];
    const int*   src    = (const int*)d_in[2];
    const int*   dst    = (const int*)d_in[3];
    const float* W      = (const float*)d_in[4];
    const float* attn_l = (const float*)d_in[5];
    const float* attn_r = (const float*)d_in[6];
    const float* attn_e = (const float*)d_in[7];

    float* ret1 = (float*)d_out;                     // N*128, node_out accum
    float* ret2 = ret1 + (size_t)NN * OUT_F;         // E*128 output

    char* wsp = (char*)d_ws;
    auto take = [&](size_t bytes) { char* p = wsp; wsp += (bytes + 511) & ~size_t(511); return p; };
    unsigned short* ftb = (unsigned short*)take((size_t)NN * OUT_F * 2);  // 12.8 MB
    float* a1buf  = (float*)take((size_t)NN * HH * 4);
    float* a2buf  = (float*)take((size_t)NN * HH * 4);
    float* exq    = (float*)take((size_t)EE * HH * 4);      // 12.8 MB, [E][H]
    float* ssum   = (float*)take((size_t)NN * HH * 4);
    unsigned short* Whp = (unsigned short*)take(32768 * 2);
    unsigned short* Wlp = (unsigned short*)take(32768 * 2);
    int* hist   = (int*)take((size_t)NN * 4);
    int* cursor = (int*)take((size_t)NN * 4);
    int* order  = (int*)take((size_t)EE * 4);               // 3.2 MB
    unsigned short* eftb = (unsigned short*)take((size_t)EE * OUT_F * 2); // 204.8 MB

    hipMemsetAsync(hist, 0, (size_t)NN * 4, stream);
    k_setup<<<PREP_B + HIST_B + SSUM_B + RET1_B, 256, 0, stream>>>(
            W, Whp, Wlp, dst, hist, (float4*)ssum, (float4*)ret1);
    k_scan<<<1, 1024, 0, stream>>>(hist, cursor);
    k_scatter<<<(EE + 255) / 256, 256, 0, stream>>>(dst, cursor, order);

    k_gemm<0><<<(NN + 63) / 64, 256, 0, stream>>>(nf, NN, Whp, Wlp,
            attn_l, attn_r, nullptr, nullptr, nullptr, nullptr,
            ftb, a1buf, a2buf, nullptr);
    k_gemm<1><<<EE / 64, 256, 0, stream>>>(ef, EE, Whp, Wlp,
            attn_e, nullptr, src, dst, a1buf, a2buf,
            eftb, exq, nullptr, ssum);

    k_agg2<<<EE / 64, 256, 0, stream>>>(order, src, dst, ftb, exq, ssum,
                                        eftb, ret2, ret1);
    k_elu1<<<(NN * OUT_F / 4 + 255) / 256, 256, 0, stream>>>(
            (const float4*)ret1, (float4*)ret1);
}